// Round 4
// baseline (605.466 us; speedup 1.0000x reference)
//
#include <hip/hip_runtime.h>
#include <hip/hip_bf16.h>

typedef unsigned short u16;
typedef unsigned int u32;
typedef __attribute__((ext_vector_type(8))) short short8;
typedef __attribute__((ext_vector_type(4))) float floatx4;
typedef __attribute__((ext_vector_type(2))) unsigned int uint2v;

__device__ __forceinline__ float b2f(u16 u) {
    u32 x = ((u32)u) << 16;
    return __builtin_bit_cast(float, x);
}
// scalar f32 -> bf16 (RNE), branch-free
__device__ __forceinline__ u16 f2b(float f) {
    u32 x = __builtin_bit_cast(u32, f);
    return (u16)((x + 0x7fffu + ((x >> 16) & 1u)) >> 16);
}
// packed f32x2 -> bf16x2: lowers to single v_cvt_pk_bf16_f32
__device__ __forceinline__ u32 pack2(float lo, float hi) {
    float2 f; f.x = lo; f.y = hi;
    __hip_bfloat162 h = __float22bfloat162_rn(f);
    u32 r;
    __builtin_memcpy(&r, &h, 4);
    return r;
}
// native 2^x (v_exp_f32 computes exp2 directly)
__device__ __forceinline__ float fexp2(float x) {
#if __has_builtin(__builtin_amdgcn_exp2f)
    return __builtin_amdgcn_exp2f(x);
#else
    return __expf(x * 0.6931471805599453f);
#endif
}

// gfx950 permlane32_swap builtin — SAFE ONLY WITH DISTINCT SSA OPERANDS.
// r1 post-mortem: inline-asm "+v","+v" self-aliased -> NaN.
// r3 post-mortem: pl(v,v) through the BUILTIN also aliases (result regs tied
//   to operand regs; op0==op1 -> out0==out1 == row-permuted v, killing the
//   max/sum reductions identically in r2/r3 -> bit-identical absmax 8.4e-2).
// => reductions use __shfl_xor (proven in the 409us baseline); permlane is
//   used ONLY for the PV transpose, whose operands are distinct SSA values.
// pl32(a,b) -> out[0]=[a.row0,b.row0], out[1]=[a.row1,b.row1] (32-lane rows).
__device__ __forceinline__ uint2v pl32(u32 a, u32 b) {
    return __builtin_amdgcn_permlane32_swap(a, b, false, false);
}

// ---------------------------------------------------------------------------
// GEMM: C[m,n] = scale * sum_k A[m,k] * B[n,k]  (+ bias[n])
// A: (M,K) row-major, f32 (AF32=true) or bf16 (false)
// B: (N,K) row-major f32 (weights straight from d_in)
// C: bf16 (Cb) or f32 (Cf). f32 acc via MFMA. 128x128 tile, BK=64.
// ---------------------------------------------------------------------------
template<bool AF32>
__global__ __launch_bounds__(256) void gemm_bt_bias(
    const void* __restrict__ Ap, const float* __restrict__ B,
    u16* __restrict__ Cb, float* __restrict__ Cf, const float* __restrict__ bias,
    int M, int N, int K, float scale)
{
    __shared__ __align__(16) u16 a_lds[128][72];
    __shared__ __align__(16) u16 b_lds[128][72];
    const int tid = threadIdx.x;
    const int lane = tid & 63, wv = tid >> 6;
    const int quad = lane >> 4, l15 = lane & 15;
    const int tm = blockIdx.x, tn = blockIdx.y;
    const int wm = (wv >> 1) * 64, wn = (wv & 1) * 64;
    (void)M;

    floatx4 acc[4][4];
#pragma unroll
    for (int i = 0; i < 4; ++i)
#pragma unroll
        for (int j = 0; j < 4; ++j) acc[i][j] = (floatx4)0.f;

    for (int k0 = 0; k0 < K; k0 += 64) {
#pragma unroll
        for (int r = 0; r < 4; ++r) {
            int idx = r * 256 + tid;
            int row = idx >> 3, ch = (idx & 7) * 8;
            if constexpr (AF32) {
                const float* A = (const float*)Ap;
                const float* src = A + (size_t)(tm * 128 + row) * K + k0 + ch;
                float4 f0 = *(const float4*)src;
                float4 f1 = *(const float4*)(src + 4);
                uint4 pk;
                pk.x = pack2(f0.x, f0.y);
                pk.y = pack2(f0.z, f0.w);
                pk.z = pack2(f1.x, f1.y);
                pk.w = pack2(f1.z, f1.w);
                *(uint4*)&a_lds[row][ch] = pk;
            } else {
                const u16* A = (const u16*)Ap;
                *(uint4*)&a_lds[row][ch] =
                    *(const uint4*)(A + (size_t)(tm * 128 + row) * K + k0 + ch);
            }
            {
                const float* src = B + (size_t)(tn * 128 + row) * K + k0 + ch;
                float4 f0 = *(const float4*)src;
                float4 f1 = *(const float4*)(src + 4);
                uint4 pk;
                pk.x = pack2(f0.x, f0.y);
                pk.y = pack2(f0.z, f0.w);
                pk.z = pack2(f1.x, f1.y);
                pk.w = pack2(f1.z, f1.w);
                *(uint4*)&b_lds[row][ch] = pk;
            }
        }
        __syncthreads();
#pragma unroll
        for (int dc = 0; dc < 2; ++dc) {
            short8 af[4], bf[4];
#pragma unroll
            for (int mi = 0; mi < 4; ++mi)
                af[mi] = *(const short8*)&a_lds[wm + mi * 16 + l15][dc * 32 + quad * 8];
#pragma unroll
            for (int ni = 0; ni < 4; ++ni)
                bf[ni] = *(const short8*)&b_lds[wn + ni * 16 + l15][dc * 32 + quad * 8];
#pragma unroll
            for (int mi = 0; mi < 4; ++mi)
#pragma unroll
                for (int ni = 0; ni < 4; ++ni)
                    acc[mi][ni] = __builtin_amdgcn_mfma_f32_16x16x32_bf16(
                        af[mi], bf[ni], acc[mi][ni], 0, 0, 0);
        }
        __syncthreads();
    }
#pragma unroll
    for (int mi = 0; mi < 4; ++mi)
#pragma unroll
        for (int ni = 0; ni < 4; ++ni) {
            int col = tn * 128 + wn + ni * 16 + l15;
            float bb = bias ? bias[col] : 0.f;
#pragma unroll
            for (int r = 0; r < 4; ++r) {
                int row = tm * 128 + wm + mi * 16 + quad * 4 + r;
                float val = acc[mi][ni][r] * scale + bb;
                if (Cf) Cf[(size_t)row * N + col] = val;
                else    Cb[(size_t)row * N + col] = f2b(val);
            }
        }
}

// ---------------------------------------------------------------------------
// instance decode: 224 instances = 128 (br0) + 64 (br1) + 32 (br2)
// ---------------------------------------------------------------------------
__device__ __forceinline__ void decode_inst(int inst, int& b, int& s, int& h,
                                            int& sl, int& dr, int& phase)
{
    if (inst < 128)      { int j = inst;       b = j >> 6; s = (j >> 3) & 7; h = j & 7; sl = 1024; dr = 1; phase = 0;      }
    else if (inst < 192) { int j = inst - 128; b = j >> 5; s = (j >> 3) & 3; h = j & 7; sl = 2048; dr = 2; phase = h >> 2; }
    else                 { int j = inst - 192; b = j >> 4; s = (j >> 3) & 1; h = j & 7; sl = 4096; dr = 4; phase = h >> 1; }
}

// ---------------------------------------------------------------------------
// Gather K and V^T into per-instance contiguous buffers (internal bf16).
// KG[inst][n][d], VT[inst][d][n]. grid: (224, 32)
// ---------------------------------------------------------------------------
__global__ __launch_bounds__(256) void gather_kv(
    const u16* __restrict__ kk, const u16* __restrict__ vv,
    u16* __restrict__ KG, u16* __restrict__ VT)
{
    int inst = blockIdx.x;
    int b, s, h, sl, dr, phase;
    decode_inst(inst, b, s, h, sl, dr, phase);
    int n0 = blockIdx.y * 32;
    __shared__ __align__(16) u16 tile[32][72];
    int tid = threadIdx.x;
    int row = tid >> 3, ch = (tid & 7) * 8;
    int n = n0 + row;
    size_t pos = (size_t)s * sl + (size_t)n * dr + phase;
    size_t src = (((size_t)b * 8192 + pos) * 8 + h) * 64 + ch;
    *(uint4*)(KG + ((size_t)inst * 1024 + n) * 64 + ch) = *(const uint4*)(kk + src);
    *(uint4*)&tile[row][ch] = *(const uint4*)(vv + src);
    __syncthreads();
    int d = tid >> 2, nn = (tid & 3) * 8;
    __align__(16) u16 tmp[8];
#pragma unroll
    for (int j = 0; j < 8; ++j) tmp[j] = tile[nn + j][d];
    *(uint4*)(VT + ((size_t)inst * 64 + d) * 1024 + n0 + nn) = *(uint4*)tmp;
}

// ---------------------------------------------------------------------------
// Flash attention, S^T formulation; scores arrive in LOG2 domain (log2e folded
// into Q-proj scale); softmax via native v_exp_f32. LSE kept in log2 units.
// grid: (16 q-tiles, 224 inst); 256 thr = 4 waves x 16 q-rows; K-tile 128.
// (1) K rows read bit2<->bit3-swapped (sl15): quads compute key groups
//     {0-3, 8-11, 4-7, 12-15} so the PV B-fragment transpose is EXACTLY two
//     permlane32_swap per 32-key chunk (distinct SSA operands — safe) instead
//     of 32 ds_bpermute/iter. Softmax reductions stay on __shfl_xor (proven);
//     permlane self-swap pl(v,v) is UB-by-aliasing (r3 post-mortem).
// (2) T14 reg-prefetch of next K/V tile: global latency hides under compute.
// ---------------------------------------------------------------------------
__global__ __launch_bounds__(256, 4) void attn_kernel(
    const u16* __restrict__ q, const u16* __restrict__ KG,
    const u16* __restrict__ VT, u16* __restrict__ Og, float* __restrict__ Lg)
{
    const int inst = blockIdx.y, qt = blockIdx.x;
    int b, s, h, sl, dr, phase;
    decode_inst(inst, b, s, h, sl, dr, phase);
    __shared__ __align__(16) u16 k_lds[128][72];
    __shared__ __align__(16) u16 vt_lds[64][136];
    const int tid = threadIdx.x, lane = tid & 63, wv = tid >> 6;
    const int quad = lane >> 4, l15 = lane & 15;
    // swap bits 2,3 of l15: A-operand row permutation for the pl32-only transpose
    const int sl15 = (l15 & 3) | ((l15 & 4) << 1) | ((l15 & 8) >> 1);

    // Q fragments (B-operand: n = l15 = qrow, k = quad*8+j). q pre-scaled.
    const int qrow = qt * 64 + wv * 16 + l15;
    const size_t qpos = (size_t)s * sl + (size_t)qrow * dr + phase;
    const u16* qbase = q + (((size_t)b * 8192 + qpos) * 8 + h) * 64;
    const short8 qf0 = *(const short8*)(qbase + quad * 8);
    const short8 qf1 = *(const short8*)(qbase + 32 + quad * 8);

    floatx4 oacc[4];
#pragma unroll
    for (int dt = 0; dt < 4; ++dt) oacc[dt] = (floatx4)0.f;
    float mst = -1e30f, lst = 0.f;

    // staging geometry (hoisted)
    const int srow = tid >> 3, sch = (tid & 7) * 8;    // K: rows +32 per r
    const int sd = tid >> 4, sch2 = (tid & 15) * 8;    // VT: d +16 per r
    const u16* KGb = KG + (size_t)inst * 65536;        // [1024][64]
    const u16* VTb = VT + (size_t)inst * 65536;        // [64][1024]

    // prefetch tile 0 into regs
    uint4 kreg[4], vreg[4];
#pragma unroll
    for (int r = 0; r < 4; ++r) {
        kreg[r] = *(const uint4*)(KGb + (size_t)(r * 32 + srow) * 64 + sch);
        vreg[r] = *(const uint4*)(VTb + (size_t)(r * 16 + sd) * 1024 + sch2);
    }

    for (int it = 0; it < 8; ++it) {
        // write current tile (loaded last iter) to LDS
#pragma unroll
        for (int r = 0; r < 4; ++r) {
            *(uint4*)&k_lds[r * 32 + srow][sch] = kreg[r];
            *(uint4*)&vt_lds[r * 16 + sd][sch2] = vreg[r];
        }
        __syncthreads();
        // issue next tile's loads; latency hides under this iter's compute
        if (it < 7) {
            const int k0n = (it + 1) * 128;
#pragma unroll
            for (int r = 0; r < 4; ++r) {
                kreg[r] = *(const uint4*)(KGb + (size_t)(k0n + r * 32 + srow) * 64 + sch);
                vreg[r] = *(const uint4*)(VTb + (size_t)(r * 16 + sd) * 1024 + k0n + sch2);
            }
        }

        // S^T tiles with permuted key order: lane (quad,l15) reg r holds
        // S[qrow=l15][key = k0 + nt*16 + sl15(quad*4+r)]
        floatx4 sacc[8];
#pragma unroll
        for (int nt = 0; nt < 8; ++nt) {
            sacc[nt] = (floatx4)0.f;
            short8 kf0 = *(const short8*)&k_lds[nt * 16 + sl15][quad * 8];
            short8 kf1 = *(const short8*)&k_lds[nt * 16 + sl15][32 + quad * 8];
            sacc[nt] = __builtin_amdgcn_mfma_f32_16x16x32_bf16(kf0, qf0, sacc[nt], 0, 0, 0);
            sacc[nt] = __builtin_amdgcn_mfma_f32_16x16x32_bf16(kf1, qf1, sacc[nt], 0, 0, 0);
        }

        // online softmax (log2 domain) for q-row l15; __shfl_xor reductions
        // (key order within the row is irrelevant to max/sum)
        float mx = sacc[0][0];
#pragma unroll
        for (int nt = 0; nt < 8; ++nt)
#pragma unroll
            for (int r = 0; r < 4; ++r) mx = fmaxf(mx, sacc[nt][r]);
        mx = fmaxf(mx, __shfl_xor(mx, 16, 64));
        mx = fmaxf(mx, __shfl_xor(mx, 32, 64));
        float mnew = fmaxf(mst, mx);
        float alpha = fexp2(mst - mnew);
        float rs = 0.f;
#pragma unroll
        for (int nt = 0; nt < 8; ++nt)
#pragma unroll
            for (int r = 0; r < 4; ++r) {
                float p = fexp2(sacc[nt][r] - mnew);
                sacc[nt][r] = p;
                rs += p;
            }
        rs += __shfl_xor(rs, 16, 64);
        rs += __shfl_xor(rs, 32, 64);
        lst = lst * alpha + rs;
        mst = mnew;
#pragma unroll
        for (int dt = 0; dt < 4; ++dt) oacc[dt] *= alpha;

        // PV: O^T[d][qrow] += V^T[d][key] * P^T[key][qrow], 4 chunks of 32 keys.
        // With the permuted key order, source words per quad are:
        //   pk00: q0={0,1} q1={8,9}  q2={4,5}  q3={12,13}   (+nc*32)
        //   pk01: q0={2,3} q1={10,11} q2={6,7} q3={14,15}
        //   pk10/pk11: same +16.
        // pl32(pk00,pk10): out0 = bw.x = keys 8q+{0,1}; out1 = bw.z = 8q+{4,5}
        // pl32(pk01,pk11): out0 = bw.y = keys 8q+{2,3}; out1 = bw.w = 8q+{6,7}
        // (verified for all 4 dest quads; operands are distinct SSA values)
#pragma unroll
        for (int nc = 0; nc < 4; ++nc) {
            u32 pk00 = pack2(sacc[2 * nc][0], sacc[2 * nc][1]);
            u32 pk01 = pack2(sacc[2 * nc][2], sacc[2 * nc][3]);
            u32 pk10 = pack2(sacc[2 * nc + 1][0], sacc[2 * nc + 1][1]);
            u32 pk11 = pack2(sacc[2 * nc + 1][2], sacc[2 * nc + 1][3]);
            uint2v xz = pl32(pk00, pk10);
            uint2v yw = pl32(pk01, pk11);
            uint4 bw;
            bw.x = xz[0];
            bw.y = yw[0];
            bw.z = xz[1];
            bw.w = yw[1];
            short8 pf = __builtin_bit_cast(short8, bw);
#pragma unroll
            for (int dt = 0; dt < 4; ++dt) {
                short8 vf = *(const short8*)&vt_lds[dt * 16 + l15][nc * 32 + quad * 8];
                oacc[dt] = __builtin_amdgcn_mfma_f32_16x16x32_bf16(vf, pf, oacc[dt], 0, 0, 0);
            }
        }
        __syncthreads();
    }

    // epilogue: O^T -> O via k_lds (free now).
    float inv_l = (lst > 0.f) ? (1.f / lst) : 0.f;
#pragma unroll
    for (int dt = 0; dt < 4; ++dt) {
        u32 lo = pack2(oacc[dt][0] * inv_l, oacc[dt][1] * inv_l);
        u32 hi = pack2(oacc[dt][2] * inv_l, oacc[dt][3] * inv_l);
        uint2 v; v.x = lo; v.y = hi;
        *(uint2*)&k_lds[wv * 16 + l15][dt * 16 + quad * 4] = v;
    }
    __syncthreads();
#pragma unroll
    for (int c = 0; c < 2; ++c) {
        uint4 val = *(const uint4*)&k_lds[wv * 16 + l15][quad * 16 + c * 8];
        *(uint4*)(Og + (((size_t)inst * 1024 + qt * 64 + wv * 16 + l15) * 64
                        + quad * 16 + c * 8)) = val;
    }
    if (quad == 0) {
        // LSE in log2 units
        Lg[(size_t)inst * 1024 + qt * 64 + wv * 16 + l15] = mst + __log2f(lst);
    }
}

// ---------------------------------------------------------------------------
// LSE-weighted merge (log2-domain LSE) -> merged (b, L, H*64) bf16
// ---------------------------------------------------------------------------
__global__ __launch_bounds__(256) void merge_kernel(
    const u16* __restrict__ Og, const float* __restrict__ Lg,
    u16* __restrict__ merged)
{
    int bid = blockIdx.x;
    int b = bid >> 13, l = bid & 8191;
    int t = threadIdx.x;
    int h = t >> 5, d0 = (t & 31) * 2;

    int inst0 = b * 64 + ((l >> 10) << 3) + h;
    int row0 = l & 1023;
    int p1 = l & 2047;
    bool c1 = ((p1 & 1) == (h >> 2));
    int inst1 = 128 + b * 32 + ((l >> 11) << 3) + h;
    int row1 = p1 >> 1;
    int p2 = l & 4095;
    bool c2 = ((p2 & 3) == (h >> 1));
    int inst2 = 192 + b * 16 + ((l >> 12) << 3) + h;
    int row2 = p2 >> 2;

    float lse0 = Lg[(size_t)inst0 * 1024 + row0];
    float lse1 = c1 ? Lg[(size_t)inst1 * 1024 + row1] : -1e30f;
    float lse2 = c2 ? Lg[(size_t)inst2 * 1024 + row2] : -1e30f;
    float m = fmaxf(lse0, fmaxf(lse1, lse2));
    float w0 = fexp2(lse0 - m);
    float w1 = c1 ? fexp2(lse1 - m) : 0.f;
    float w2 = c2 ? fexp2(lse2 - m) : 0.f;
    float inv = 1.f / (w0 + w1 + w2);
    w0 *= inv; w1 *= inv; w2 *= inv;

    u32 u0 = *(const u32*)(Og + ((size_t)inst0 * 1024 + row0) * 64 + d0);
    u32 u1 = c1 ? *(const u32*)(Og + ((size_t)inst1 * 1024 + row1) * 64 + d0) : 0u;
    u32 u2 = c2 ? *(const u32*)(Og + ((size_t)inst2 * 1024 + row2) * 64 + d0) : 0u;
    float a0 = b2f((u16)(u0 & 0xffff)), e0 = b2f((u16)(u0 >> 16));
    float a1 = b2f((u16)(u1 & 0xffff)), e1 = b2f((u16)(u1 >> 16));
    float a2 = b2f((u16)(u2 & 0xffff)), e2 = b2f((u16)(u2 >> 16));
    float ra = w0 * a0 + w1 * a1 + w2 * a2;
    float rb = w0 * e0 + w1 * e1 + w2 * e2;
    u32 outp = pack2(ra, rb);
    *(u32*)(merged + (((size_t)b * 8192 + l) * 8 + h) * 64 + d0) = outp;
}

// ---------------------------------------------------------------------------
extern "C" void kernel_launch(void* const* d_in, const int* in_sizes, int n_in,
                              void* d_out, int out_size, void* d_ws, size_t ws_size,
                              hipStream_t stream)
{
    (void)in_sizes; (void)n_in; (void)out_size; (void)ws_size;
    const float* query = (const float*)d_in[0];
    const float* key_  = (const float*)d_in[1];
    const float* value = (const float*)d_in[2];
    const float* Wq    = (const float*)d_in[3];
    const float* Wk    = (const float*)d_in[4];
    const float* Wv    = (const float*)d_in[5];
    const float* Wo    = (const float*)d_in[6];
    const float* bo    = (const float*)d_in[7];

    char* ws = (char*)d_ws;
    const size_t SZ_PROJ = (size_t)16384 * 512 * 2;       // 16 MiB each (bf16)
    const size_t SZ_KG   = (size_t)224 * 1024 * 64 * 2;   // 28 MiB
    const size_t SZ_LG   = (size_t)224 * 1024 * 4;
    u16*   qb     = (u16*)(ws);
    u16*   kb     = (u16*)(ws + SZ_PROJ);
    u16*   vb     = (u16*)(ws + 2 * SZ_PROJ);
    u16*   KG     = (u16*)(ws + 3 * SZ_PROJ);
    u16*   VT     = (u16*)(ws + 3 * SZ_PROJ + SZ_KG);
    u16*   Og     = (u16*)(ws + 3 * SZ_PROJ + 2 * SZ_KG);
    float* Lg     = (float*)(ws + 3 * SZ_PROJ + 3 * SZ_KG);
    u16*   merged = (u16*)(ws + 3 * SZ_PROJ + 3 * SZ_KG + SZ_LG);

    const int M = 16384, N = 512, K = 512;
    // 64^-0.5 * log2(e): scores come out of QK^T in log2 units
    const float SCALE = 0.125f * 1.44269504088896f;

    gemm_bt_bias<true><<<dim3(128, 4), 256, 0, stream>>>(query, Wq, qb, nullptr, nullptr, M, N, K, SCALE);
    gemm_bt_bias<true><<<dim3(128, 4), 256, 0, stream>>>(key_,  Wk, kb, nullptr, nullptr, M, N, K, 1.0f);
    gemm_bt_bias<true><<<dim3(128, 4), 256, 0, stream>>>(value, Wv, vb, nullptr, nullptr, M, N, K, 1.0f);
    gather_kv<<<dim3(224, 32), 256, 0, stream>>>(kb, vb, KG, VT);
    attn_kernel<<<dim3(16, 224), 256, 0, stream>>>(qb, KG, VT, Og, Lg);
    merge_kernel<<<16384, 256, 0, stream>>>(Og, Lg, merged);
    gemm_bt_bias<false><<<dim3(128, 4), 256, 0, stream>>>(merged, Wo, nullptr, (float*)d_out, bo, M, N, K, 1.0f);
}

// Round 5
// 388.778 us; speedup vs baseline: 1.5574x; 1.5574x over previous
//
#include <hip/hip_runtime.h>
#include <hip/hip_bf16.h>

typedef unsigned short u16;
typedef unsigned int u32;
typedef __attribute__((ext_vector_type(8))) short short8;
typedef __attribute__((ext_vector_type(4))) float floatx4;
typedef __attribute__((ext_vector_type(2))) unsigned int uint2v;

__device__ __forceinline__ float b2f(u16 u) {
    u32 x = ((u32)u) << 16;
    return __builtin_bit_cast(float, x);
}
// scalar f32 -> bf16 (RNE), branch-free
__device__ __forceinline__ u16 f2b(float f) {
    u32 x = __builtin_bit_cast(u32, f);
    return (u16)((x + 0x7fffu + ((x >> 16) & 1u)) >> 16);
}
// packed f32x2 -> bf16x2: lowers to single v_cvt_pk_bf16_f32
__device__ __forceinline__ u32 pack2(float lo, float hi) {
    float2 f; f.x = lo; f.y = hi;
    __hip_bfloat162 h = __float22bfloat162_rn(f);
    u32 r;
    __builtin_memcpy(&r, &h, 4);
    return r;
}
// native 2^x (v_exp_f32 computes exp2 directly)
__device__ __forceinline__ float fexp2(float x) {
#if __has_builtin(__builtin_amdgcn_exp2f)
    return __builtin_amdgcn_exp2f(x);
#else
    return __expf(x * 0.6931471805599453f);
#endif
}

// gfx950 permlane32_swap builtin — SAFE ONLY WITH DISTINCT SSA OPERANDS
// (r1/r3 post-mortems: self-swap pl(v,v) aliases result/operand regs = UB).
// HW-verified correct in r4 (passed, absmax == baseline).
// pl32(a,b) -> out[0]=[a.row0,b.row0], out[1]=[a.row1,b.row1] (32-lane rows).
__device__ __forceinline__ uint2v pl32(u32 a, u32 b) {
    return __builtin_amdgcn_permlane32_swap(a, b, false, false);
}

// ---------------------------------------------------------------------------
// GEMM: C[m,n] = scale * sum_k A[m,k] * B[n,k]  (+ bias[n])
// A: (M,K) row-major, f32 (AF32=true) or bf16 (false)
// B: (N,K) row-major f32 (weights straight from d_in)
// C: bf16 (Cb) or f32 (Cf). f32 acc via MFMA. 128x128 tile, BK=64.
// ---------------------------------------------------------------------------
template<bool AF32>
__global__ __launch_bounds__(256) void gemm_bt_bias(
    const void* __restrict__ Ap, const float* __restrict__ B,
    u16* __restrict__ Cb, float* __restrict__ Cf, const float* __restrict__ bias,
    int M, int N, int K, float scale)
{
    __shared__ __align__(16) u16 a_lds[128][72];
    __shared__ __align__(16) u16 b_lds[128][72];
    const int tid = threadIdx.x;
    const int lane = tid & 63, wv = tid >> 6;
    const int quad = lane >> 4, l15 = lane & 15;
    const int tm = blockIdx.x, tn = blockIdx.y;
    const int wm = (wv >> 1) * 64, wn = (wv & 1) * 64;
    (void)M;

    floatx4 acc[4][4];
#pragma unroll
    for (int i = 0; i < 4; ++i)
#pragma unroll
        for (int j = 0; j < 4; ++j) acc[i][j] = (floatx4)0.f;

    for (int k0 = 0; k0 < K; k0 += 64) {
#pragma unroll
        for (int r = 0; r < 4; ++r) {
            int idx = r * 256 + tid;
            int row = idx >> 3, ch = (idx & 7) * 8;
            if constexpr (AF32) {
                const float* A = (const float*)Ap;
                const float* src = A + (size_t)(tm * 128 + row) * K + k0 + ch;
                float4 f0 = *(const float4*)src;
                float4 f1 = *(const float4*)(src + 4);
                uint4 pk;
                pk.x = pack2(f0.x, f0.y);
                pk.y = pack2(f0.z, f0.w);
                pk.z = pack2(f1.x, f1.y);
                pk.w = pack2(f1.z, f1.w);
                *(uint4*)&a_lds[row][ch] = pk;
            } else {
                const u16* A = (const u16*)Ap;
                *(uint4*)&a_lds[row][ch] =
                    *(const uint4*)(A + (size_t)(tm * 128 + row) * K + k0 + ch);
            }
            {
                const float* src = B + (size_t)(tn * 128 + row) * K + k0 + ch;
                float4 f0 = *(const float4*)src;
                float4 f1 = *(const float4*)(src + 4);
                uint4 pk;
                pk.x = pack2(f0.x, f0.y);
                pk.y = pack2(f0.z, f0.w);
                pk.z = pack2(f1.x, f1.y);
                pk.w = pack2(f1.z, f1.w);
                *(uint4*)&b_lds[row][ch] = pk;
            }
        }
        __syncthreads();
#pragma unroll
        for (int dc = 0; dc < 2; ++dc) {
            short8 af[4], bf[4];
#pragma unroll
            for (int mi = 0; mi < 4; ++mi)
                af[mi] = *(const short8*)&a_lds[wm + mi * 16 + l15][dc * 32 + quad * 8];
#pragma unroll
            for (int ni = 0; ni < 4; ++ni)
                bf[ni] = *(const short8*)&b_lds[wn + ni * 16 + l15][dc * 32 + quad * 8];
#pragma unroll
            for (int mi = 0; mi < 4; ++mi)
#pragma unroll
                for (int ni = 0; ni < 4; ++ni)
                    acc[mi][ni] = __builtin_amdgcn_mfma_f32_16x16x32_bf16(
                        af[mi], bf[ni], acc[mi][ni], 0, 0, 0);
        }
        __syncthreads();
    }
#pragma unroll
    for (int mi = 0; mi < 4; ++mi)
#pragma unroll
        for (int ni = 0; ni < 4; ++ni) {
            int col = tn * 128 + wn + ni * 16 + l15;
            float bb = bias ? bias[col] : 0.f;
#pragma unroll
            for (int r = 0; r < 4; ++r) {
                int row = tm * 128 + wm + mi * 16 + quad * 4 + r;
                float val = acc[mi][ni][r] * scale + bb;
                if (Cf) Cf[(size_t)row * N + col] = val;
                else    Cb[(size_t)row * N + col] = f2b(val);
            }
        }
}

// ---------------------------------------------------------------------------
// instance decode: 224 instances = 128 (br0) + 64 (br1) + 32 (br2)
// ---------------------------------------------------------------------------
__device__ __forceinline__ void decode_inst(int inst, int& b, int& s, int& h,
                                            int& sl, int& dr, int& phase)
{
    if (inst < 128)      { int j = inst;       b = j >> 6; s = (j >> 3) & 7; h = j & 7; sl = 1024; dr = 1; phase = 0;      }
    else if (inst < 192) { int j = inst - 128; b = j >> 5; s = (j >> 3) & 3; h = j & 7; sl = 2048; dr = 2; phase = h >> 2; }
    else                 { int j = inst - 192; b = j >> 4; s = (j >> 3) & 1; h = j & 7; sl = 4096; dr = 4; phase = h >> 1; }
}

// ---------------------------------------------------------------------------
// Gather K and V^T into per-instance contiguous buffers (internal bf16).
// KG[inst][n][d], VT[inst][d][n]. grid: (224, 32)
// ---------------------------------------------------------------------------
__global__ __launch_bounds__(256) void gather_kv(
    const u16* __restrict__ kk, const u16* __restrict__ vv,
    u16* __restrict__ KG, u16* __restrict__ VT)
{
    int inst = blockIdx.x;
    int b, s, h, sl, dr, phase;
    decode_inst(inst, b, s, h, sl, dr, phase);
    int n0 = blockIdx.y * 32;
    __shared__ __align__(16) u16 tile[32][72];
    int tid = threadIdx.x;
    int row = tid >> 3, ch = (tid & 7) * 8;
    int n = n0 + row;
    size_t pos = (size_t)s * sl + (size_t)n * dr + phase;
    size_t src = (((size_t)b * 8192 + pos) * 8 + h) * 64 + ch;
    *(uint4*)(KG + ((size_t)inst * 1024 + n) * 64 + ch) = *(const uint4*)(kk + src);
    *(uint4*)&tile[row][ch] = *(const uint4*)(vv + src);
    __syncthreads();
    int d = tid >> 2, nn = (tid & 3) * 8;
    __align__(16) u16 tmp[8];
#pragma unroll
    for (int j = 0; j < 8; ++j) tmp[j] = tile[nn + j][d];
    *(uint4*)(VT + ((size_t)inst * 64 + d) * 1024 + n0 + nn) = *(uint4*)tmp;
}

// ---------------------------------------------------------------------------
// Flash attention, S^T formulation; scores arrive in LOG2 domain (log2e folded
// into Q-proj scale); softmax via native v_exp_f32. LSE kept in log2 units.
// grid: (16 q-tiles, 224 inst); 256 thr = 4 waves x 16 q-rows; K-tile 128.
// r5: staging reverted to r0's direct global->LDS (r4's persistent prefetch
//     regs spilled to scratch: WRITE_SIZE 29MB->940MB == 32 VGPR x 8it x
//     256thr x 3584wg exactly; VGPR_Count frozen at 52 confirmed demotion).
//     KEPT: sl15 + dual-permlane32 PV transpose (HW-verified correct in r4) —
//     replaces 32 ds_bpermute/iter on the LDS crossbar with 8 VALU ops.
// ---------------------------------------------------------------------------
__global__ __launch_bounds__(256, 4) void attn_kernel(
    const u16* __restrict__ q, const u16* __restrict__ KG,
    const u16* __restrict__ VT, u16* __restrict__ Og, float* __restrict__ Lg)
{
    const int inst = blockIdx.y, qt = blockIdx.x;
    int b, s, h, sl, dr, phase;
    decode_inst(inst, b, s, h, sl, dr, phase);
    __shared__ __align__(16) u16 k_lds[128][72];
    __shared__ __align__(16) u16 vt_lds[64][136];
    const int tid = threadIdx.x, lane = tid & 63, wv = tid >> 6;
    const int quad = lane >> 4, l15 = lane & 15;
    // swap bits 2,3 of l15: A-operand row permutation for the pl32-only transpose
    const int sl15 = (l15 & 3) | ((l15 & 4) << 1) | ((l15 & 8) >> 1);

    // Q fragments (B-operand: n = l15 = qrow, k = quad*8+j). q pre-scaled.
    const int qrow = qt * 64 + wv * 16 + l15;
    const size_t qpos = (size_t)s * sl + (size_t)qrow * dr + phase;
    const u16* qbase = q + (((size_t)b * 8192 + qpos) * 8 + h) * 64;
    const short8 qf0 = *(const short8*)(qbase + quad * 8);
    const short8 qf1 = *(const short8*)(qbase + 32 + quad * 8);

    floatx4 oacc[4];
#pragma unroll
    for (int dt = 0; dt < 4; ++dt) oacc[dt] = (floatx4)0.f;
    float mst = -1e30f, lst = 0.f;

    const u16* KGb = KG + (size_t)inst * 65536;        // [1024][64]
    const u16* VTb = VT + (size_t)inst * 65536;        // [64][1024]

    for (int it = 0; it < 8; ++it) {
        const int k0 = it * 128;
        // direct global->LDS staging (transient regs only; no spill)
#pragma unroll
        for (int r = 0; r < 4; ++r) {
            int idx = r * 256 + tid;
            int row = idx >> 3, ch = (idx & 7) * 8;
            *(uint4*)&k_lds[row][ch] =
                *(const uint4*)(KGb + (size_t)(k0 + row) * 64 + ch);
        }
#pragma unroll
        for (int r = 0; r < 4; ++r) {
            int idx = r * 256 + tid;
            int d = idx >> 4, ch = (idx & 15) * 8;
            *(uint4*)&vt_lds[d][ch] =
                *(const uint4*)(VTb + (size_t)d * 1024 + k0 + ch);
        }
        __syncthreads();

        // S^T tiles with permuted key order: lane (quad,l15) reg r holds
        // S[qrow=l15][key = k0 + nt*16 + keyperm], keyperm via sl15 row read
        floatx4 sacc[8];
#pragma unroll
        for (int nt = 0; nt < 8; ++nt) {
            sacc[nt] = (floatx4)0.f;
            short8 kf0 = *(const short8*)&k_lds[nt * 16 + sl15][quad * 8];
            short8 kf1 = *(const short8*)&k_lds[nt * 16 + sl15][32 + quad * 8];
            sacc[nt] = __builtin_amdgcn_mfma_f32_16x16x32_bf16(kf0, qf0, sacc[nt], 0, 0, 0);
            sacc[nt] = __builtin_amdgcn_mfma_f32_16x16x32_bf16(kf1, qf1, sacc[nt], 0, 0, 0);
        }

        // online softmax (log2 domain) for q-row l15; __shfl_xor reductions
        // (key order within the row is irrelevant to max/sum)
        float mx = sacc[0][0];
#pragma unroll
        for (int nt = 0; nt < 8; ++nt)
#pragma unroll
            for (int r = 0; r < 4; ++r) mx = fmaxf(mx, sacc[nt][r]);
        mx = fmaxf(mx, __shfl_xor(mx, 16, 64));
        mx = fmaxf(mx, __shfl_xor(mx, 32, 64));
        float mnew = fmaxf(mst, mx);
        float alpha = fexp2(mst - mnew);
        float rs = 0.f;
#pragma unroll
        for (int nt = 0; nt < 8; ++nt)
#pragma unroll
            for (int r = 0; r < 4; ++r) {
                float p = fexp2(sacc[nt][r] - mnew);
                sacc[nt][r] = p;
                rs += p;
            }
        rs += __shfl_xor(rs, 16, 64);
        rs += __shfl_xor(rs, 32, 64);
        lst = lst * alpha + rs;
        mst = mnew;
#pragma unroll
        for (int dt = 0; dt < 4; ++dt) oacc[dt] *= alpha;

        // PV: O^T[d][qrow] += V^T[d][key] * P^T[key][qrow], 4 chunks of 32 keys.
        // With the permuted key order, source words per quad are:
        //   pk00: q0={0,1} q1={8,9}  q2={4,5}  q3={12,13}   (+nc*32)
        //   pk01: q0={2,3} q1={10,11} q2={6,7} q3={14,15}
        //   pk10/pk11: same +16.
        // pl32(pk00,pk10): out0 = bw.x = keys 8q+{0,1}; out1 = bw.z = 8q+{4,5}
        // pl32(pk01,pk11): out0 = bw.y = keys 8q+{2,3}; out1 = bw.w = 8q+{6,7}
        // (HW-verified in r4; operands are distinct SSA values)
#pragma unroll
        for (int nc = 0; nc < 4; ++nc) {
            u32 pk00 = pack2(sacc[2 * nc][0], sacc[2 * nc][1]);
            u32 pk01 = pack2(sacc[2 * nc][2], sacc[2 * nc][3]);
            u32 pk10 = pack2(sacc[2 * nc + 1][0], sacc[2 * nc + 1][1]);
            u32 pk11 = pack2(sacc[2 * nc + 1][2], sacc[2 * nc + 1][3]);
            uint2v xz = pl32(pk00, pk10);
            uint2v yw = pl32(pk01, pk11);
            uint4 bw;
            bw.x = xz[0];
            bw.y = yw[0];
            bw.z = xz[1];
            bw.w = yw[1];
            short8 pf = __builtin_bit_cast(short8, bw);
#pragma unroll
            for (int dt = 0; dt < 4; ++dt) {
                short8 vf = *(const short8*)&vt_lds[dt * 16 + l15][nc * 32 + quad * 8];
                oacc[dt] = __builtin_amdgcn_mfma_f32_16x16x32_bf16(vf, pf, oacc[dt], 0, 0, 0);
            }
        }
        __syncthreads();
    }

    // epilogue: O^T -> O via k_lds (free now).
    float inv_l = (lst > 0.f) ? (1.f / lst) : 0.f;
#pragma unroll
    for (int dt = 0; dt < 4; ++dt) {
        u32 lo = pack2(oacc[dt][0] * inv_l, oacc[dt][1] * inv_l);
        u32 hi = pack2(oacc[dt][2] * inv_l, oacc[dt][3] * inv_l);
        uint2 v; v.x = lo; v.y = hi;
        *(uint2*)&k_lds[wv * 16 + l15][dt * 16 + quad * 4] = v;
    }
    __syncthreads();
#pragma unroll
    for (int c = 0; c < 2; ++c) {
        uint4 val = *(const uint4*)&k_lds[wv * 16 + l15][quad * 16 + c * 8];
        *(uint4*)(Og + (((size_t)inst * 1024 + qt * 64 + wv * 16 + l15) * 64
                        + quad * 16 + c * 8)) = val;
    }
    if (quad == 0) {
        // LSE in log2 units
        Lg[(size_t)inst * 1024 + qt * 64 + wv * 16 + l15] = mst + __log2f(lst);
    }
}

// ---------------------------------------------------------------------------
// LSE-weighted merge (log2-domain LSE) -> merged (b, L, H*64) bf16
// ---------------------------------------------------------------------------
__global__ __launch_bounds__(256) void merge_kernel(
    const u16* __restrict__ Og, const float* __restrict__ Lg,
    u16* __restrict__ merged)
{
    int bid = blockIdx.x;
    int b = bid >> 13, l = bid & 8191;
    int t = threadIdx.x;
    int h = t >> 5, d0 = (t & 31) * 2;

    int inst0 = b * 64 + ((l >> 10) << 3) + h;
    int row0 = l & 1023;
    int p1 = l & 2047;
    bool c1 = ((p1 & 1) == (h >> 2));
    int inst1 = 128 + b * 32 + ((l >> 11) << 3) + h;
    int row1 = p1 >> 1;
    int p2 = l & 4095;
    bool c2 = ((p2 & 3) == (h >> 1));
    int inst2 = 192 + b * 16 + ((l >> 12) << 3) + h;
    int row2 = p2 >> 2;

    float lse0 = Lg[(size_t)inst0 * 1024 + row0];
    float lse1 = c1 ? Lg[(size_t)inst1 * 1024 + row1] : -1e30f;
    float lse2 = c2 ? Lg[(size_t)inst2 * 1024 + row2] : -1e30f;
    float m = fmaxf(lse0, fmaxf(lse1, lse2));
    float w0 = fexp2(lse0 - m);
    float w1 = c1 ? fexp2(lse1 - m) : 0.f;
    float w2 = c2 ? fexp2(lse2 - m) : 0.f;
    float inv = 1.f / (w0 + w1 + w2);
    w0 *= inv; w1 *= inv; w2 *= inv;

    u32 u0 = *(const u32*)(Og + ((size_t)inst0 * 1024 + row0) * 64 + d0);
    u32 u1 = c1 ? *(const u32*)(Og + ((size_t)inst1 * 1024 + row1) * 64 + d0) : 0u;
    u32 u2 = c2 ? *(const u32*)(Og + ((size_t)inst2 * 1024 + row2) * 64 + d0) : 0u;
    float a0 = b2f((u16)(u0 & 0xffff)), e0 = b2f((u16)(u0 >> 16));
    float a1 = b2f((u16)(u1 & 0xffff)), e1 = b2f((u16)(u1 >> 16));
    float a2 = b2f((u16)(u2 & 0xffff)), e2 = b2f((u16)(u2 >> 16));
    float ra = w0 * a0 + w1 * a1 + w2 * a2;
    float rb = w0 * e0 + w1 * e1 + w2 * e2;
    u32 outp = pack2(ra, rb);
    *(u32*)(merged + (((size_t)b * 8192 + l) * 8 + h) * 64 + d0) = outp;
}

// ---------------------------------------------------------------------------
extern "C" void kernel_launch(void* const* d_in, const int* in_sizes, int n_in,
                              void* d_out, int out_size, void* d_ws, size_t ws_size,
                              hipStream_t stream)
{
    (void)in_sizes; (void)n_in; (void)out_size; (void)ws_size;
    const float* query = (const float*)d_in[0];
    const float* key_  = (const float*)d_in[1];
    const float* value = (const float*)d_in[2];
    const float* Wq    = (const float*)d_in[3];
    const float* Wk    = (const float*)d_in[4];
    const float* Wv    = (const float*)d_in[5];
    const float* Wo    = (const float*)d_in[6];
    const float* bo    = (const float*)d_in[7];

    char* ws = (char*)d_ws;
    const size_t SZ_PROJ = (size_t)16384 * 512 * 2;       // 16 MiB each (bf16)
    const size_t SZ_KG   = (size_t)224 * 1024 * 64 * 2;   // 28 MiB
    const size_t SZ_LG   = (size_t)224 * 1024 * 4;
    u16*   qb     = (u16*)(ws);
    u16*   kb     = (u16*)(ws + SZ_PROJ);
    u16*   vb     = (u16*)(ws + 2 * SZ_PROJ);
    u16*   KG     = (u16*)(ws + 3 * SZ_PROJ);
    u16*   VT     = (u16*)(ws + 3 * SZ_PROJ + SZ_KG);
    u16*   Og     = (u16*)(ws + 3 * SZ_PROJ + 2 * SZ_KG);
    float* Lg     = (float*)(ws + 3 * SZ_PROJ + 3 * SZ_KG);
    u16*   merged = (u16*)(ws + 3 * SZ_PROJ + 3 * SZ_KG + SZ_LG);

    const int M = 16384, N = 512, K = 512;
    // 64^-0.5 * log2(e): scores come out of QK^T in log2 units
    const float SCALE = 0.125f * 1.44269504088896f;

    gemm_bt_bias<true><<<dim3(128, 4), 256, 0, stream>>>(query, Wq, qb, nullptr, nullptr, M, N, K, SCALE);
    gemm_bt_bias<true><<<dim3(128, 4), 256, 0, stream>>>(key_,  Wk, kb, nullptr, nullptr, M, N, K, 1.0f);
    gemm_bt_bias<true><<<dim3(128, 4), 256, 0, stream>>>(value, Wv, vb, nullptr, nullptr, M, N, K, 1.0f);
    gather_kv<<<dim3(224, 32), 256, 0, stream>>>(kb, vb, KG, VT);
    attn_kernel<<<dim3(16, 224), 256, 0, stream>>>(qb, KG, VT, Og, Lg);
    merge_kernel<<<16384, 256, 0, stream>>>(Og, Lg, merged);
    gemm_bt_bias<false><<<dim3(128, 4), 256, 0, stream>>>(merged, Wo, nullptr, (float*)d_out, bo, M, N, K, 1.0f);
}

// Round 7
// 353.137 us; speedup vs baseline: 1.7145x; 1.1009x over previous
//
#include <hip/hip_runtime.h>
#include <hip/hip_bf16.h>

typedef unsigned short u16;
typedef unsigned int u32;
typedef __attribute__((ext_vector_type(8))) short short8;
typedef __attribute__((ext_vector_type(4))) float floatx4;
typedef __attribute__((ext_vector_type(2))) unsigned int uint2v;

__device__ __forceinline__ float b2f(u16 u) {
    u32 x = ((u32)u) << 16;
    return __builtin_bit_cast(float, x);
}
// scalar f32 -> bf16 (RNE), branch-free
__device__ __forceinline__ u16 f2b(float f) {
    u32 x = __builtin_bit_cast(u32, f);
    return (u16)((x + 0x7fffu + ((x >> 16) & 1u)) >> 16);
}
// packed f32x2 -> bf16x2: lowers to single v_cvt_pk_bf16_f32
__device__ __forceinline__ u32 pack2(float lo, float hi) {
    float2 f; f.x = lo; f.y = hi;
    __hip_bfloat162 h = __float22bfloat162_rn(f);
    u32 r;
    __builtin_memcpy(&r, &h, 4);
    return r;
}
// native 2^x (v_exp_f32 computes exp2 directly)
__device__ __forceinline__ float fexp2(float x) {
#if __has_builtin(__builtin_amdgcn_exp2f)
    return __builtin_amdgcn_exp2f(x);
#else
    return __expf(x * 0.6931471805599453f);
#endif
}

// gfx950 permlane32_swap builtin — SAFE ONLY WITH DISTINCT SSA OPERANDS
// (r1/r3 post-mortems: self-swap pl(v,v) aliases result/operand regs = UB).
// HW-verified correct in r4/r5 (passed, absmax == baseline).
// pl32(a,b) -> out[0]=[a.row0,b.row0], out[1]=[a.row1,b.row1] (32-lane rows).
__device__ __forceinline__ uint2v pl32(u32 a, u32 b) {
    return __builtin_amdgcn_permlane32_swap(a, b, false, false);
}

// async global->LDS, 16B per lane. LDS dest = wave-uniform base + lane*16
// (m104/m108); global src is per-lane. Counted by vmcnt; __syncthreads()
// drains it (compiler emits s_waitcnt vmcnt(0) before s_barrier).
__device__ __forceinline__ void gl16(const u16* g, u16* l) {
    __builtin_amdgcn_global_load_lds(
        (const __attribute__((address_space(1))) void*)g,
        (__attribute__((address_space(3))) void*)l, 16, 0, 0);
}

// ---------------------------------------------------------------------------
// GEMM: C[m,n] = scale * sum_k A[m,k] * B[n,k]  (+ bias[n])
// A: (M,K) row-major, f32 (AF32=true) or bf16 (false)
// B: (N,K) row-major f32 (weights straight from d_in)
// C: bf16 (Cb) or f32 (Cf). f32 acc via MFMA. 128x128 tile, BK=64.
// ---------------------------------------------------------------------------
template<bool AF32>
__global__ __launch_bounds__(256) void gemm_bt_bias(
    const void* __restrict__ Ap, const float* __restrict__ B,
    u16* __restrict__ Cb, float* __restrict__ Cf, const float* __restrict__ bias,
    int M, int N, int K, float scale)
{
    __shared__ __align__(16) u16 a_lds[128][72];
    __shared__ __align__(16) u16 b_lds[128][72];
    const int tid = threadIdx.x;
    const int lane = tid & 63, wv = tid >> 6;
    const int quad = lane >> 4, l15 = lane & 15;
    const int tm = blockIdx.x, tn = blockIdx.y;
    const int wm = (wv >> 1) * 64, wn = (wv & 1) * 64;
    (void)M;

    floatx4 acc[4][4];
#pragma unroll
    for (int i = 0; i < 4; ++i)
#pragma unroll
        for (int j = 0; j < 4; ++j) acc[i][j] = (floatx4)0.f;

    for (int k0 = 0; k0 < K; k0 += 64) {
#pragma unroll
        for (int r = 0; r < 4; ++r) {
            int idx = r * 256 + tid;
            int row = idx >> 3, ch = (idx & 7) * 8;
            if constexpr (AF32) {
                const float* A = (const float*)Ap;
                const float* src = A + (size_t)(tm * 128 + row) * K + k0 + ch;
                float4 f0 = *(const float4*)src;
                float4 f1 = *(const float4*)(src + 4);
                uint4 pk;
                pk.x = pack2(f0.x, f0.y);
                pk.y = pack2(f0.z, f0.w);
                pk.z = pack2(f1.x, f1.y);
                pk.w = pack2(f1.z, f1.w);
                *(uint4*)&a_lds[row][ch] = pk;
            } else {
                const u16* A = (const u16*)Ap;
                *(uint4*)&a_lds[row][ch] =
                    *(const uint4*)(A + (size_t)(tm * 128 + row) * K + k0 + ch);
            }
            {
                const float* src = B + (size_t)(tn * 128 + row) * K + k0 + ch;
                float4 f0 = *(const float4*)src;
                float4 f1 = *(const float4*)(src + 4);
                uint4 pk;
                pk.x = pack2(f0.x, f0.y);
                pk.y = pack2(f0.z, f0.w);
                pk.z = pack2(f1.x, f1.y);
                pk.w = pack2(f1.z, f1.w);
                *(uint4*)&b_lds[row][ch] = pk;
            }
        }
        __syncthreads();
#pragma unroll
        for (int dc = 0; dc < 2; ++dc) {
            short8 af[4], bf[4];
#pragma unroll
            for (int mi = 0; mi < 4; ++mi)
                af[mi] = *(const short8*)&a_lds[wm + mi * 16 + l15][dc * 32 + quad * 8];
#pragma unroll
            for (int ni = 0; ni < 4; ++ni)
                bf[ni] = *(const short8*)&b_lds[wn + ni * 16 + l15][dc * 32 + quad * 8];
#pragma unroll
            for (int mi = 0; mi < 4; ++mi)
#pragma unroll
                for (int ni = 0; ni < 4; ++ni)
                    acc[mi][ni] = __builtin_amdgcn_mfma_f32_16x16x32_bf16(
                        af[mi], bf[ni], acc[mi][ni], 0, 0, 0);
        }
        __syncthreads();
    }
#pragma unroll
    for (int mi = 0; mi < 4; ++mi)
#pragma unroll
        for (int ni = 0; ni < 4; ++ni) {
            int col = tn * 128 + wn + ni * 16 + l15;
            float bb = bias ? bias[col] : 0.f;
#pragma unroll
            for (int r = 0; r < 4; ++r) {
                int row = tm * 128 + wm + mi * 16 + quad * 4 + r;
                float val = acc[mi][ni][r] * scale + bb;
                if (Cf) Cf[(size_t)row * N + col] = val;
                else    Cb[(size_t)row * N + col] = f2b(val);
            }
        }
}

// ---------------------------------------------------------------------------
// instance decode: 224 instances = 128 (br0) + 64 (br1) + 32 (br2)
// ---------------------------------------------------------------------------
__device__ __forceinline__ void decode_inst(int inst, int& b, int& s, int& h,
                                            int& sl, int& dr, int& phase)
{
    if (inst < 128)      { int j = inst;       b = j >> 6; s = (j >> 3) & 7; h = j & 7; sl = 1024; dr = 1; phase = 0;      }
    else if (inst < 192) { int j = inst - 128; b = j >> 5; s = (j >> 3) & 3; h = j & 7; sl = 2048; dr = 2; phase = h >> 2; }
    else                 { int j = inst - 192; b = j >> 4; s = (j >> 3) & 1; h = j & 7; sl = 4096; dr = 4; phase = h >> 1; }
}

// ---------------------------------------------------------------------------
// Gather K and V^T into per-instance contiguous buffers (internal bf16),
// PRE-SWIZZLED for the attn kernel's global_load_lds staging (rule 21:
// both-sides-or-neither). Within each 128-key staging tile:
//   KG'[n][e]  = K[n][e ^ ((n&7)*8)]      (e = head-dim index, 0..63)
//   VT'[d][c]  = V^T[d][c ^ ((d&7)*8)]    (c = key index; XOR hits bits 3-5
//                                          only, never crosses the 128 tile)
// attn stages these LINEARLY into LDS and reads with the same XOR -> the
// stride-128B bank conflicts of the unpadded tiles are broken.
// KG[inst][n][d'], VT[inst][d][c']. grid: (224, 32)
// ---------------------------------------------------------------------------
__global__ __launch_bounds__(256) void gather_kv(
    const u16* __restrict__ kk, const u16* __restrict__ vv,
    u16* __restrict__ KG, u16* __restrict__ VT)
{
    int inst = blockIdx.x;
    int b, s, h, sl, dr, phase;
    decode_inst(inst, b, s, h, sl, dr, phase);
    int n0 = blockIdx.y * 32;
    __shared__ __align__(16) u16 tile[32][72];
    int tid = threadIdx.x;
    int row = tid >> 3, ch = (tid & 7) * 8;
    int n = n0 + row;
    size_t pos = (size_t)s * sl + (size_t)n * dr + phase;
    size_t src = (((size_t)b * 8192 + pos) * 8 + h) * 64 + ch;
    int chs = ch ^ ((n & 7) * 8);   // K column swizzle (8-aligned, stays 0..63)
    *(uint4*)(KG + ((size_t)inst * 1024 + n) * 64 + chs) = *(const uint4*)(kk + src);
    *(uint4*)&tile[row][ch] = *(const uint4*)(vv + src);
    __syncthreads();
    int d = tid >> 2, nn = (tid & 3) * 8;
    __align__(16) u16 tmp[8];
#pragma unroll
    for (int j = 0; j < 8; ++j) tmp[j] = tile[nn + j][d];
    int col = (n0 + nn) ^ ((d & 7) * 8);  // VT column swizzle (within 128-block)
    *(uint4*)(VT + ((size_t)inst * 64 + d) * 1024 + col) = *(uint4*)tmp;
}

// ---------------------------------------------------------------------------
// Flash attention, S^T formulation; scores arrive in LOG2 domain (log2e folded
// into Q-proj scale); softmax via native v_exp_f32. LSE kept in log2 units.
// grid: (16 q-tiles, 224 inst); 256 thr = 4 waves x 16 q-rows; K-tile 128.
// r6: staging via global_load_lds (no VGPR transit, no ds_write ops — was
//     8/44 LDS ops per wave-iter + write-side bank conflicts). Unpadded
//     k_lds[128][64] / vt_lds[64][128] with XOR col-swizzle ((row&7)*8),
//     matched by gather_kv's pre-swizzled KG/VT (both-sides-or-neither).
//     KEPT: sl15 + dual-permlane32 PV transpose (r4/r5-verified), __shfl_xor
//     softmax reductions.
// ---------------------------------------------------------------------------
__global__ __launch_bounds__(256, 4) void attn_kernel(
    const u16* __restrict__ q, const u16* __restrict__ KG,
    const u16* __restrict__ VT, u16* __restrict__ Og, float* __restrict__ Lg)
{
    const int inst = blockIdx.y, qt = blockIdx.x;
    int b, s, h, sl, dr, phase;
    decode_inst(inst, b, s, h, sl, dr, phase);
    __shared__ __align__(16) u16 k_lds[128][64];   // 16 KB, swizzled cols
    __shared__ __align__(16) u16 vt_lds[64][128];  // 16 KB, swizzled cols
    const int tid = threadIdx.x, lane = tid & 63, wv = tid >> 6;
    const int quad = lane >> 4, l15 = lane & 15;
    // swap bits 2,3 of l15: A-operand row permutation for the pl32-only transpose
    const int sl15 = (l15 & 3) | ((l15 & 4) << 1) | ((l15 & 8) >> 1);
    const int ksw = (sl15 & 7) * 8;   // K-read col swizzle for this lane's row
    const int vsw = (l15 & 7) * 8;    // VT-read col swizzle (row = dt*16+l15)

    // Q fragments (B-operand: n = l15 = qrow, k = quad*8+j). q pre-scaled.
    const int qrow = qt * 64 + wv * 16 + l15;
    const size_t qpos = (size_t)s * sl + (size_t)qrow * dr + phase;
    const u16* qbase = q + (((size_t)b * 8192 + qpos) * 8 + h) * 64;
    const short8 qf0 = *(const short8*)(qbase + quad * 8);
    const short8 qf1 = *(const short8*)(qbase + 32 + quad * 8);

    floatx4 oacc[4];
#pragma unroll
    for (int dt = 0; dt < 4; ++dt) oacc[dt] = (floatx4)0.f;
    float mst = -1e30f, lst = 0.f;

    const u16* KGb = KG + (size_t)inst * 65536;        // [1024][64] swizzled
    const u16* VTb = VT + (size_t)inst * 65536;        // [64][1024] swizzled
    u16* klb = &k_lds[0][0];
    u16* vlb = &vt_lds[0][0];

    for (int it = 0; it < 8; ++it) {
        const int k0 = it * 128;
        // async staging: 16 KB K + 16 KB VT, linear copies (layouts are
        // pre-swizzled in global). 4+4 gl16 per wave; each moves 1024 B
        // (64 lanes x 16 B) to LDS base + lane*16.
#pragma unroll
        for (int r = 0; r < 4; ++r) {
            int c = wv * 4 + r;                       // chunk 0..15
            gl16(KGb + (size_t)k0 * 64 + c * 512 + lane * 8, klb + c * 512);
            gl16(VTb + (size_t)(c * 4 + (lane >> 4)) * 1024 + k0 + (lane & 15) * 8,
                 vlb + c * 512);
        }
        __syncthreads();   // drains vmcnt(0): staged data visible

        // S^T tiles with permuted key order: lane (quad,l15) reg r holds
        // S[qrow=l15][key = k0 + nt*16 + keyperm], keyperm via sl15 row read
        floatx4 sacc[8];
#pragma unroll
        for (int nt = 0; nt < 8; ++nt) {
            sacc[nt] = (floatx4)0.f;
            short8 kf0 = *(const short8*)&k_lds[nt * 16 + sl15][(quad * 8) ^ ksw];
            short8 kf1 = *(const short8*)&k_lds[nt * 16 + sl15][(32 + quad * 8) ^ ksw];
            sacc[nt] = __builtin_amdgcn_mfma_f32_16x16x32_bf16(kf0, qf0, sacc[nt], 0, 0, 0);
            sacc[nt] = __builtin_amdgcn_mfma_f32_16x16x32_bf16(kf1, qf1, sacc[nt], 0, 0, 0);
        }

        // online softmax (log2 domain) for q-row l15; __shfl_xor reductions
        // (key order within the row is irrelevant to max/sum)
        float mx = sacc[0][0];
#pragma unroll
        for (int nt = 0; nt < 8; ++nt)
#pragma unroll
            for (int r = 0; r < 4; ++r) mx = fmaxf(mx, sacc[nt][r]);
        mx = fmaxf(mx, __shfl_xor(mx, 16, 64));
        mx = fmaxf(mx, __shfl_xor(mx, 32, 64));
        float mnew = fmaxf(mst, mx);
        float alpha = fexp2(mst - mnew);
        float rs = 0.f;
#pragma unroll
        for (int nt = 0; nt < 8; ++nt)
#pragma unroll
            for (int r = 0; r < 4; ++r) {
                float p = fexp2(sacc[nt][r] - mnew);
                sacc[nt][r] = p;
                rs += p;
            }
        rs += __shfl_xor(rs, 16, 64);
        rs += __shfl_xor(rs, 32, 64);
        lst = lst * alpha + rs;
        mst = mnew;
#pragma unroll
        for (int dt = 0; dt < 4; ++dt) oacc[dt] *= alpha;

        // PV: O^T[d][qrow] += V^T[d][key] * P^T[key][qrow], 4 chunks of 32 keys.
        // pl32(pk00,pk10): out0 = bw.x = keys 8q+{0,1}; out1 = bw.z = 8q+{4,5}
        // pl32(pk01,pk11): out0 = bw.y = keys 8q+{2,3}; out1 = bw.w = 8q+{6,7}
        // (HW-verified r4/r5; operands are distinct SSA values)
#pragma unroll
        for (int nc = 0; nc < 4; ++nc) {
            u32 pk00 = pack2(sacc[2 * nc][0], sacc[2 * nc][1]);
            u32 pk01 = pack2(sacc[2 * nc][2], sacc[2 * nc][3]);
            u32 pk10 = pack2(sacc[2 * nc + 1][0], sacc[2 * nc + 1][1]);
            u32 pk11 = pack2(sacc[2 * nc + 1][2], sacc[2 * nc + 1][3]);
            uint2v xz = pl32(pk00, pk10);
            uint2v yw = pl32(pk01, pk11);
            uint4 bw;
            bw.x = xz[0];
            bw.y = yw[0];
            bw.z = xz[1];
            bw.w = yw[1];
            short8 pf = __builtin_bit_cast(short8, bw);
#pragma unroll
            for (int dt = 0; dt < 4; ++dt) {
                short8 vf = *(const short8*)
                    &vt_lds[dt * 16 + l15][(nc * 32 + quad * 8) ^ vsw];
                oacc[dt] = __builtin_amdgcn_mfma_f32_16x16x32_bf16(vf, pf, oacc[dt], 0, 0, 0);
            }
        }
        __syncthreads();
    }

    // epilogue: O^T -> O via k_lds (free now). Unpadded 64-col scratch is a
    // 128B stride -> swizzle cols by the row's (l15&7)*8 like the main tiles.
    const int esw = (l15 & 7) * 8;
    float inv_l = (lst > 0.f) ? (1.f / lst) : 0.f;
#pragma unroll
    for (int dt = 0; dt < 4; ++dt) {
        u32 lo = pack2(oacc[dt][0] * inv_l, oacc[dt][1] * inv_l);
        u32 hi = pack2(oacc[dt][2] * inv_l, oacc[dt][3] * inv_l);
        uint2 v; v.x = lo; v.y = hi;
        *(uint2*)&k_lds[wv * 16 + l15][(dt * 16 + quad * 4) ^ esw] = v;
    }
    __syncthreads();
#pragma unroll
    for (int c = 0; c < 2; ++c) {
        uint4 val = *(const uint4*)&k_lds[wv * 16 + l15][(quad * 16 + c * 8) ^ esw];
        *(uint4*)(Og + (((size_t)inst * 1024 + qt * 64 + wv * 16 + l15) * 64
                        + quad * 16 + c * 8)) = val;
    }
    if (quad == 0) {
        // LSE in log2 units
        Lg[(size_t)inst * 1024 + qt * 64 + wv * 16 + l15] = mst + __log2f(lst);
    }
}

// ---------------------------------------------------------------------------
// LSE-weighted merge (log2-domain LSE) -> merged (b, L, H*64) bf16
// ---------------------------------------------------------------------------
__global__ __launch_bounds__(256) void merge_kernel(
    const u16* __restrict__ Og, const float* __restrict__ Lg,
    u16* __restrict__ merged)
{
    int bid = blockIdx.x;
    int b = bid >> 13, l = bid & 8191;
    int t = threadIdx.x;
    int h = t >> 5, d0 = (t & 31) * 2;

    int inst0 = b * 64 + ((l >> 10) << 3) + h;
    int row0 = l & 1023;
    int p1 = l & 2047;
    bool c1 = ((p1 & 1) == (h >> 2));
    int inst1 = 128 + b * 32 + ((l >> 11) << 3) + h;
    int row1 = p1 >> 1;
    int p2 = l & 4095;
    bool c2 = ((p2 & 3) == (h >> 1));
    int inst2 = 192 + b * 16 + ((l >> 12) << 3) + h;
    int row2 = p2 >> 2;

    float lse0 = Lg[(size_t)inst0 * 1024 + row0];
    float lse1 = c1 ? Lg[(size_t)inst1 * 1024 + row1] : -1e30f;
    float lse2 = c2 ? Lg[(size_t)inst2 * 1024 + row2] : -1e30f;
    float m = fmaxf(lse0, fmaxf(lse1, lse2));
    float w0 = fexp2(lse0 - m);
    float w1 = c1 ? fexp2(lse1 - m) : 0.f;
    float w2 = c2 ? fexp2(lse2 - m) : 0.f;
    float inv = 1.f / (w0 + w1 + w2);
    w0 *= inv; w1 *= inv; w2 *= inv;

    u32 u0 = *(const u32*)(Og + ((size_t)inst0 * 1024 + row0) * 64 + d0);
    u32 u1 = c1 ? *(const u32*)(Og + ((size_t)inst1 * 1024 + row1) * 64 + d0) : 0u;
    u32 u2 = c2 ? *(const u32*)(Og + ((size_t)inst2 * 1024 + row2) * 64 + d0) : 0u;
    float a0 = b2f((u16)(u0 & 0xffff)), e0 = b2f((u16)(u0 >> 16));
    float a1 = b2f((u16)(u1 & 0xffff)), e1 = b2f((u16)(u1 >> 16));
    float a2 = b2f((u16)(u2 & 0xffff)), e2 = b2f((u16)(u2 >> 16));
    float ra = w0 * a0 + w1 * a1 + w2 * a2;
    float rb = w0 * e0 + w1 * e1 + w2 * e2;
    u32 outp = pack2(ra, rb);
    *(u32*)(merged + (((size_t)b * 8192 + l) * 8 + h) * 64 + d0) = outp;
}

// ---------------------------------------------------------------------------
extern "C" void kernel_launch(void* const* d_in, const int* in_sizes, int n_in,
                              void* d_out, int out_size, void* d_ws, size_t ws_size,
                              hipStream_t stream)
{
    (void)in_sizes; (void)n_in; (void)out_size; (void)ws_size;
    const float* query = (const float*)d_in[0];
    const float* key_  = (const float*)d_in[1];
    const float* value = (const float*)d_in[2];
    const float* Wq    = (const float*)d_in[3];
    const float* Wk    = (const float*)d_in[4];
    const float* Wv    = (const float*)d_in[5];
    const float* Wo    = (const float*)d_in[6];
    const float* bo    = (const float*)d_in[7];

    char* ws = (char*)d_ws;
    const size_t SZ_PROJ = (size_t)16384 * 512 * 2;       // 16 MiB each (bf16)
    const size_t SZ_KG   = (size_t)224 * 1024 * 64 * 2;   // 28 MiB
    const size_t SZ_LG   = (size_t)224 * 1024 * 4;
    u16*   qb     = (u16*)(ws);
    u16*   kb     = (u16*)(ws + SZ_PROJ);
    u16*   vb     = (u16*)(ws + 2 * SZ_PROJ);
    u16*   KG     = (u16*)(ws + 3 * SZ_PROJ);
    u16*   VT     = (u16*)(ws + 3 * SZ_PROJ + SZ_KG);
    u16*   Og     = (u16*)(ws + 3 * SZ_PROJ + 2 * SZ_KG);
    float* Lg     = (float*)(ws + 3 * SZ_PROJ + 3 * SZ_KG);
    u16*   merged = (u16*)(ws + 3 * SZ_PROJ + 3 * SZ_KG + SZ_LG);

    const int M = 16384, N = 512, K = 512;
    // 64^-0.5 * log2(e): scores come out of QK^T in log2 units
    const float SCALE = 0.125f * 1.44269504088896f;

    gemm_bt_bias<true><<<dim3(128, 4), 256, 0, stream>>>(query, Wq, qb, nullptr, nullptr, M, N, K, SCALE);
    gemm_bt_bias<true><<<dim3(128, 4), 256, 0, stream>>>(key_,  Wk, kb, nullptr, nullptr, M, N, K, 1.0f);
    gemm_bt_bias<true><<<dim3(128, 4), 256, 0, stream>>>(value, Wv, vb, nullptr, nullptr, M, N, K, 1.0f);
    gather_kv<<<dim3(224, 32), 256, 0, stream>>>(kb, vb, KG, VT);
    attn_kernel<<<dim3(16, 224), 256, 0, stream>>>(qb, KG, VT, Og, Lg);
    merge_kernel<<<16384, 256, 0, stream>>>(Og, Lg, merged);
    gemm_bt_bias<false><<<dim3(128, 4), 256, 0, stream>>>(merged, Wo, nullptr, (float*)d_out, bo, M, N, K, 1.0f);
}

// Round 8
// 341.494 us; speedup vs baseline: 1.7730x; 1.0341x over previous
//
#include <hip/hip_runtime.h>
#include <hip/hip_bf16.h>

typedef unsigned short u16;
typedef unsigned int u32;
typedef __attribute__((ext_vector_type(8))) short short8;
typedef __attribute__((ext_vector_type(4))) float floatx4;
typedef __attribute__((ext_vector_type(2))) unsigned int uint2v;

__device__ __forceinline__ float b2f(u16 u) {
    u32 x = ((u32)u) << 16;
    return __builtin_bit_cast(float, x);
}
// scalar f32 -> bf16 (RNE), branch-free
__device__ __forceinline__ u16 f2b(float f) {
    u32 x = __builtin_bit_cast(u32, f);
    return (u16)((x + 0x7fffu + ((x >> 16) & 1u)) >> 16);
}
// packed f32x2 -> bf16x2: lowers to single v_cvt_pk_bf16_f32
__device__ __forceinline__ u32 pack2(float lo, float hi) {
    float2 f; f.x = lo; f.y = hi;
    __hip_bfloat162 h = __float22bfloat162_rn(f);
    u32 r;
    __builtin_memcpy(&r, &h, 4);
    return r;
}
// native 2^x (v_exp_f32 computes exp2 directly)
__device__ __forceinline__ float fexp2(float x) {
#if __has_builtin(__builtin_amdgcn_exp2f)
    return __builtin_amdgcn_exp2f(x);
#else
    return __expf(x * 0.6931471805599453f);
#endif
}

// gfx950 permlane32_swap builtin — SAFE ONLY WITH DISTINCT SSA OPERANDS
// (r1/r3 post-mortems: self-swap pl(v,v) aliases result/operand regs = UB).
// HW-verified correct in r4/r5/r7 (passed, absmax == baseline).
// pl32(a,b) -> out[0]=[a.row0,b.row0], out[1]=[a.row1,b.row1] (32-lane rows).
__device__ __forceinline__ uint2v pl32(u32 a, u32 b) {
    return __builtin_amdgcn_permlane32_swap(a, b, false, false);
}

// async global->LDS, 16B per lane. LDS dest = wave-uniform base + lane*16
// (m104/m108); global src is per-lane. Counted by vmcnt; __syncthreads()
// drains it (compiler emits s_waitcnt vmcnt(0) before s_barrier).
__device__ __forceinline__ void gl16(const u16* g, u16* l) {
    __builtin_amdgcn_global_load_lds(
        (const __attribute__((address_space(1))) void*)g,
        (__attribute__((address_space(3))) void*)l, 16, 0, 0);
}

// ---------------------------------------------------------------------------
// GEMM: C[m,n] = scale * sum_k A[m,k] * B[n,k]  (+ bias[n])
// A: (M,K) row-major, f32 (AF32=true) or bf16 (false)
// B: (N,K) row-major f32 (weights straight from d_in)
// C: bf16 (Cb) or f32 (Cf). f32 acc via MFMA. 128x128 tile, BK=64.
// ---------------------------------------------------------------------------
template<bool AF32>
__global__ __launch_bounds__(256) void gemm_bt_bias(
    const void* __restrict__ Ap, const float* __restrict__ B,
    u16* __restrict__ Cb, float* __restrict__ Cf, const float* __restrict__ bias,
    int M, int N, int K, float scale)
{
    __shared__ __align__(16) u16 a_lds[128][72];
    __shared__ __align__(16) u16 b_lds[128][72];
    const int tid = threadIdx.x;
    const int lane = tid & 63, wv = tid >> 6;
    const int quad = lane >> 4, l15 = lane & 15;
    const int tm = blockIdx.x, tn = blockIdx.y;
    const int wm = (wv >> 1) * 64, wn = (wv & 1) * 64;
    (void)M;

    floatx4 acc[4][4];
#pragma unroll
    for (int i = 0; i < 4; ++i)
#pragma unroll
        for (int j = 0; j < 4; ++j) acc[i][j] = (floatx4)0.f;

    for (int k0 = 0; k0 < K; k0 += 64) {
#pragma unroll
        for (int r = 0; r < 4; ++r) {
            int idx = r * 256 + tid;
            int row = idx >> 3, ch = (idx & 7) * 8;
            if constexpr (AF32) {
                const float* A = (const float*)Ap;
                const float* src = A + (size_t)(tm * 128 + row) * K + k0 + ch;
                float4 f0 = *(const float4*)src;
                float4 f1 = *(const float4*)(src + 4);
                uint4 pk;
                pk.x = pack2(f0.x, f0.y);
                pk.y = pack2(f0.z, f0.w);
                pk.z = pack2(f1.x, f1.y);
                pk.w = pack2(f1.z, f1.w);
                *(uint4*)&a_lds[row][ch] = pk;
            } else {
                const u16* A = (const u16*)Ap;
                *(uint4*)&a_lds[row][ch] =
                    *(const uint4*)(A + (size_t)(tm * 128 + row) * K + k0 + ch);
            }
            {
                const float* src = B + (size_t)(tn * 128 + row) * K + k0 + ch;
                float4 f0 = *(const float4*)src;
                float4 f1 = *(const float4*)(src + 4);
                uint4 pk;
                pk.x = pack2(f0.x, f0.y);
                pk.y = pack2(f0.z, f0.w);
                pk.z = pack2(f1.x, f1.y);
                pk.w = pack2(f1.z, f1.w);
                *(uint4*)&b_lds[row][ch] = pk;
            }
        }
        __syncthreads();
#pragma unroll
        for (int dc = 0; dc < 2; ++dc) {
            short8 af[4], bf[4];
#pragma unroll
            for (int mi = 0; mi < 4; ++mi)
                af[mi] = *(const short8*)&a_lds[wm + mi * 16 + l15][dc * 32 + quad * 8];
#pragma unroll
            for (int ni = 0; ni < 4; ++ni)
                bf[ni] = *(const short8*)&b_lds[wn + ni * 16 + l15][dc * 32 + quad * 8];
#pragma unroll
            for (int mi = 0; mi < 4; ++mi)
#pragma unroll
                for (int ni = 0; ni < 4; ++ni)
                    acc[mi][ni] = __builtin_amdgcn_mfma_f32_16x16x32_bf16(
                        af[mi], bf[ni], acc[mi][ni], 0, 0, 0);
        }
        __syncthreads();
    }
#pragma unroll
    for (int mi = 0; mi < 4; ++mi)
#pragma unroll
        for (int ni = 0; ni < 4; ++ni) {
            int col = tn * 128 + wn + ni * 16 + l15;
            float bb = bias ? bias[col] : 0.f;
#pragma unroll
            for (int r = 0; r < 4; ++r) {
                int row = tm * 128 + wm + mi * 16 + quad * 4 + r;
                float val = acc[mi][ni][r] * scale + bb;
                if (Cf) Cf[(size_t)row * N + col] = val;
                else    Cb[(size_t)row * N + col] = f2b(val);
            }
        }
}

// ---------------------------------------------------------------------------
// instance decode: 224 instances = 128 (br0) + 64 (br1) + 32 (br2)
// ---------------------------------------------------------------------------
__device__ __forceinline__ void decode_inst(int inst, int& b, int& s, int& h,
                                            int& sl, int& dr, int& phase)
{
    if (inst < 128)      { int j = inst;       b = j >> 6; s = (j >> 3) & 7; h = j & 7; sl = 1024; dr = 1; phase = 0;      }
    else if (inst < 192) { int j = inst - 128; b = j >> 5; s = (j >> 3) & 3; h = j & 7; sl = 2048; dr = 2; phase = h >> 2; }
    else                 { int j = inst - 192; b = j >> 4; s = (j >> 3) & 1; h = j & 7; sl = 4096; dr = 4; phase = h >> 1; }
}

// ---------------------------------------------------------------------------
// Gather K and V^T into per-instance contiguous buffers (internal bf16),
// PRE-SWIZZLED for the attn kernel's global_load_lds staging (rule 21:
// both-sides-or-neither). Within each 128-key staging tile:
//   KG'[n][e]  = K[n][e ^ ((n&7)*8)]      (e = head-dim index, 0..63)
//   VT'[d][c]  = V^T[d][c ^ ((d&7)*8)]    (c = key index; XOR hits bits 3-5
//                                          only, never crosses the 128 tile)
// attn stages these LINEARLY into LDS and reads with the same XOR -> the
// stride-128B bank conflicts of the unpadded tiles are broken.
// KG[inst][n][d'], VT[inst][d][c']. grid: (224, 32)
// ---------------------------------------------------------------------------
__global__ __launch_bounds__(256) void gather_kv(
    const u16* __restrict__ kk, const u16* __restrict__ vv,
    u16* __restrict__ KG, u16* __restrict__ VT)
{
    int inst = blockIdx.x;
    int b, s, h, sl, dr, phase;
    decode_inst(inst, b, s, h, sl, dr, phase);
    int n0 = blockIdx.y * 32;
    __shared__ __align__(16) u16 tile[32][72];
    int tid = threadIdx.x;
    int row = tid >> 3, ch = (tid & 7) * 8;
    int n = n0 + row;
    size_t pos = (size_t)s * sl + (size_t)n * dr + phase;
    size_t src = (((size_t)b * 8192 + pos) * 8 + h) * 64 + ch;
    int chs = ch ^ ((n & 7) * 8);   // K column swizzle (8-aligned, stays 0..63)
    *(uint4*)(KG + ((size_t)inst * 1024 + n) * 64 + chs) = *(const uint4*)(kk + src);
    *(uint4*)&tile[row][ch] = *(const uint4*)(vv + src);
    __syncthreads();
    int d = tid >> 2, nn = (tid & 3) * 8;
    __align__(16) u16 tmp[8];
#pragma unroll
    for (int j = 0; j < 8; ++j) tmp[j] = tile[nn + j][d];
    int col = (n0 + nn) ^ ((d & 7) * 8);  // VT column swizzle (within 128-block)
    *(uint4*)(VT + ((size_t)inst * 64 + d) * 1024 + col) = *(uint4*)tmp;
}

// ---------------------------------------------------------------------------
// Flash attention, S^T formulation; scores arrive in LOG2 domain (log2e folded
// into Q-proj scale); softmax via native v_exp_f32. LSE kept in log2 units.
// grid: (16 q-tiles, 224 inst); 256 thr = 4 waves x 16 q-rows; K-tile 128.
// r8 (VALU cut — r7 showed VALUBusy 60% vs MfmaUtil 24%):
//  (a) row-sum of P via MFMA with all-ones A-operand into racc (4 extra
//      MFMA/iter on the 24%-idle matrix pipe) — replaces 32 serial v_add +
//      2 shuffles; denominator now uses the SAME bf16 P as the numerator.
//  (b) T13 defer-max: skip oacc/racc rescale when __all(mx-mst<=8) (log2
//      domain: P bounded by 2^8, safe in bf16/f32).
//  (c) tree-shaped max reduce for ILP.
// KEPT from r7: global_load_lds staging with pre-swizzled KG/VT, sl15 +
// dual-permlane32 PV transpose, __shfl_xor max reduce.
// ---------------------------------------------------------------------------
__global__ __launch_bounds__(256, 4) void attn_kernel(
    const u16* __restrict__ q, const u16* __restrict__ KG,
    const u16* __restrict__ VT, u16* __restrict__ Og, float* __restrict__ Lg)
{
    const int inst = blockIdx.y, qt = blockIdx.x;
    int b, s, h, sl, dr, phase;
    decode_inst(inst, b, s, h, sl, dr, phase);
    __shared__ __align__(16) u16 k_lds[128][64];   // 16 KB, swizzled cols
    __shared__ __align__(16) u16 vt_lds[64][128];  // 16 KB, swizzled cols
    const int tid = threadIdx.x, lane = tid & 63, wv = tid >> 6;
    const int quad = lane >> 4, l15 = lane & 15;
    // swap bits 2,3 of l15: A-operand row permutation for the pl32-only transpose
    const int sl15 = (l15 & 3) | ((l15 & 4) << 1) | ((l15 & 8) >> 1);
    const int ksw = (sl15 & 7) * 8;   // K-read col swizzle for this lane's row
    const int vsw = (l15 & 7) * 8;    // VT-read col swizzle (row = dt*16+l15)

    // Q fragments (B-operand: n = l15 = qrow, k = quad*8+j). q pre-scaled.
    const int qrow = qt * 64 + wv * 16 + l15;
    const size_t qpos = (size_t)s * sl + (size_t)qrow * dr + phase;
    const u16* qbase = q + (((size_t)b * 8192 + qpos) * 8 + h) * 64;
    const short8 qf0 = *(const short8*)(qbase + quad * 8);
    const short8 qf1 = *(const short8*)(qbase + 32 + quad * 8);

    // all-ones bf16 A-operand for the MFMA row-sum (bf16 1.0 = 0x3F80)
    uint4 onesw;
    onesw.x = 0x3F803F80u; onesw.y = 0x3F803F80u;
    onesw.z = 0x3F803F80u; onesw.w = 0x3F803F80u;
    const short8 vones = __builtin_bit_cast(short8, onesw);

    floatx4 oacc[4];
#pragma unroll
    for (int dt = 0; dt < 4; ++dt) oacc[dt] = (floatx4)0.f;
    floatx4 racc = (floatx4)0.f;   // running sum of P (denominator), MFMA-fed
    float mst = -1e30f;

    const u16* KGb = KG + (size_t)inst * 65536;        // [1024][64] swizzled
    const u16* VTb = VT + (size_t)inst * 65536;        // [64][1024] swizzled
    u16* klb = &k_lds[0][0];
    u16* vlb = &vt_lds[0][0];

    for (int it = 0; it < 8; ++it) {
        const int k0 = it * 128;
        // async staging: 16 KB K + 16 KB VT, linear copies (layouts are
        // pre-swizzled in global). 4+4 gl16 per wave; each moves 1024 B
        // (64 lanes x 16 B) to LDS base + lane*16.
#pragma unroll
        for (int r = 0; r < 4; ++r) {
            int c = wv * 4 + r;                       // chunk 0..15
            gl16(KGb + (size_t)k0 * 64 + c * 512 + lane * 8, klb + c * 512);
            gl16(VTb + (size_t)(c * 4 + (lane >> 4)) * 1024 + k0 + (lane & 15) * 8,
                 vlb + c * 512);
        }
        __syncthreads();   // drains vmcnt(0): staged data visible

        // S^T tiles with permuted key order: lane (quad,l15) reg r holds
        // S[qrow=l15][key = k0 + nt*16 + keyperm], keyperm via sl15 row read
        floatx4 sacc[8];
#pragma unroll
        for (int nt = 0; nt < 8; ++nt) {
            sacc[nt] = (floatx4)0.f;
            short8 kf0 = *(const short8*)&k_lds[nt * 16 + sl15][(quad * 8) ^ ksw];
            short8 kf1 = *(const short8*)&k_lds[nt * 16 + sl15][(32 + quad * 8) ^ ksw];
            sacc[nt] = __builtin_amdgcn_mfma_f32_16x16x32_bf16(kf0, qf0, sacc[nt], 0, 0, 0);
            sacc[nt] = __builtin_amdgcn_mfma_f32_16x16x32_bf16(kf1, qf1, sacc[nt], 0, 0, 0);
        }

        // online softmax (log2 domain) for q-row l15.
        // tree max (depth 5) then cross-quad __shfl_xor.
        float t0, t1;
        {
            float m0 = fmaxf(fmaxf(sacc[0][0], sacc[0][1]), fmaxf(sacc[0][2], sacc[0][3]));
            float m1 = fmaxf(fmaxf(sacc[1][0], sacc[1][1]), fmaxf(sacc[1][2], sacc[1][3]));
            float m2 = fmaxf(fmaxf(sacc[2][0], sacc[2][1]), fmaxf(sacc[2][2], sacc[2][3]));
            float m3 = fmaxf(fmaxf(sacc[3][0], sacc[3][1]), fmaxf(sacc[3][2], sacc[3][3]));
            t0 = fmaxf(fmaxf(m0, m1), fmaxf(m2, m3));
            float m4 = fmaxf(fmaxf(sacc[4][0], sacc[4][1]), fmaxf(sacc[4][2], sacc[4][3]));
            float m5 = fmaxf(fmaxf(sacc[5][0], sacc[5][1]), fmaxf(sacc[5][2], sacc[5][3]));
            float m6 = fmaxf(fmaxf(sacc[6][0], sacc[6][1]), fmaxf(sacc[6][2], sacc[6][3]));
            float m7 = fmaxf(fmaxf(sacc[7][0], sacc[7][1]), fmaxf(sacc[7][2], sacc[7][3]));
            t1 = fmaxf(fmaxf(m4, m5), fmaxf(m6, m7));
        }
        float mx = fmaxf(t0, t1);
        mx = fmaxf(mx, __shfl_xor(mx, 16, 64));
        mx = fmaxf(mx, __shfl_xor(mx, 32, 64));

        // T13 defer-max: only rescale when some row's max grew by > 8 (log2).
        // P then bounded by 2^8 — fine in bf16, f32 accum has headroom.
        if (!__all(mx - mst <= 8.f)) {
            float mnew = fmaxf(mst, mx);
            float alpha = fexp2(mst - mnew);
#pragma unroll
            for (int dt = 0; dt < 4; ++dt) oacc[dt] *= alpha;
            racc *= alpha;
            mst = mnew;
        }

#pragma unroll
        for (int nt = 0; nt < 8; ++nt)
#pragma unroll
            for (int r = 0; r < 4; ++r)
                sacc[nt][r] = fexp2(sacc[nt][r] - mst);

        // PV: O^T[d][qrow] += V^T[d][key] * P^T[key][qrow], 4 chunks of 32 keys.
        // pl32(pk00,pk10): out0 = bw.x = keys 8q+{0,1}; out1 = bw.z = 8q+{4,5}
        // pl32(pk01,pk11): out0 = bw.y = keys 8q+{2,3}; out1 = bw.w = 8q+{6,7}
        // (HW-verified r4/r5/r7; operands are distinct SSA values)
        // racc MFMA: all-ones A -> D[i][j] = sum_k P[k][j]; every reg/quad of
        // racc holds the same per-qrow denominator partial.
#pragma unroll
        for (int nc = 0; nc < 4; ++nc) {
            u32 pk00 = pack2(sacc[2 * nc][0], sacc[2 * nc][1]);
            u32 pk01 = pack2(sacc[2 * nc][2], sacc[2 * nc][3]);
            u32 pk10 = pack2(sacc[2 * nc + 1][0], sacc[2 * nc + 1][1]);
            u32 pk11 = pack2(sacc[2 * nc + 1][2], sacc[2 * nc + 1][3]);
            uint2v xz = pl32(pk00, pk10);
            uint2v yw = pl32(pk01, pk11);
            uint4 bw;
            bw.x = xz[0];
            bw.y = yw[0];
            bw.z = xz[1];
            bw.w = yw[1];
            short8 pf = __builtin_bit_cast(short8, bw);
#pragma unroll
            for (int dt = 0; dt < 4; ++dt) {
                short8 vf = *(const short8*)
                    &vt_lds[dt * 16 + l15][(nc * 32 + quad * 8) ^ vsw];
                oacc[dt] = __builtin_amdgcn_mfma_f32_16x16x32_bf16(vf, pf, oacc[dt], 0, 0, 0);
            }
            racc = __builtin_amdgcn_mfma_f32_16x16x32_bf16(vones, pf, racc, 0, 0, 0);
        }
        __syncthreads();
    }

    // epilogue: O^T -> O via k_lds (free now). Unpadded 64-col scratch is a
    // 128B stride -> swizzle cols by the row's (l15&7)*8 like the main tiles.
    const int esw = (l15 & 7) * 8;
    float lst = racc[0];   // all 4 regs / all quads identical by construction
    float inv_l = (lst > 0.f) ? (1.f / lst) : 0.f;
#pragma unroll
    for (int dt = 0; dt < 4; ++dt) {
        u32 lo = pack2(oacc[dt][0] * inv_l, oacc[dt][1] * inv_l);
        u32 hi = pack2(oacc[dt][2] * inv_l, oacc[dt][3] * inv_l);
        uint2 v; v.x = lo; v.y = hi;
        *(uint2*)&k_lds[wv * 16 + l15][(dt * 16 + quad * 4) ^ esw] = v;
    }
    __syncthreads();
#pragma unroll
    for (int c = 0; c < 2; ++c) {
        uint4 val = *(const uint4*)&k_lds[wv * 16 + l15][(quad * 16 + c * 8) ^ esw];
        *(uint4*)(Og + (((size_t)inst * 1024 + qt * 64 + wv * 16 + l15) * 64
                        + quad * 16 + c * 8)) = val;
    }
    if (quad == 0) {
        // LSE in log2 units
        Lg[(size_t)inst * 1024 + qt * 64 + wv * 16 + l15] = mst + __log2f(lst);
    }
}

// ---------------------------------------------------------------------------
// LSE-weighted merge (log2-domain LSE) -> merged (b, L, H*64) bf16
// ---------------------------------------------------------------------------
__global__ __launch_bounds__(256) void merge_kernel(
    const u16* __restrict__ Og, const float* __restrict__ Lg,
    u16* __restrict__ merged)
{
    int bid = blockIdx.x;
    int b = bid >> 13, l = bid & 8191;
    int t = threadIdx.x;
    int h = t >> 5, d0 = (t & 31) * 2;

    int inst0 = b * 64 + ((l >> 10) << 3) + h;
    int row0 = l & 1023;
    int p1 = l & 2047;
    bool c1 = ((p1 & 1) == (h >> 2));
    int inst1 = 128 + b * 32 + ((l >> 11) << 3) + h;
    int row1 = p1 >> 1;
    int p2 = l & 4095;
    bool c2 = ((p2 & 3) == (h >> 1));
    int inst2 = 192 + b * 16 + ((l >> 12) << 3) + h;
    int row2 = p2 >> 2;

    float lse0 = Lg[(size_t)inst0 * 1024 + row0];
    float lse1 = c1 ? Lg[(size_t)inst1 * 1024 + row1] : -1e30f;
    float lse2 = c2 ? Lg[(size_t)inst2 * 1024 + row2] : -1e30f;
    float m = fmaxf(lse0, fmaxf(lse1, lse2));
    float w0 = fexp2(lse0 - m);
    float w1 = c1 ? fexp2(lse1 - m) : 0.f;
    float w2 = c2 ? fexp2(lse2 - m) : 0.f;
    float inv = 1.f / (w0 + w1 + w2);
    w0 *= inv; w1 *= inv; w2 *= inv;

    u32 u0 = *(const u32*)(Og + ((size_t)inst0 * 1024 + row0) * 64 + d0);
    u32 u1 = c1 ? *(const u32*)(Og + ((size_t)inst1 * 1024 + row1) * 64 + d0) : 0u;
    u32 u2 = c2 ? *(const u32*)(Og + ((size_t)inst2 * 1024 + row2) * 64 + d0) : 0u;
    float a0 = b2f((u16)(u0 & 0xffff)), e0 = b2f((u16)(u0 >> 16));
    float a1 = b2f((u16)(u1 & 0xffff)), e1 = b2f((u16)(u1 >> 16));
    float a2 = b2f((u16)(u2 & 0xffff)), e2 = b2f((u16)(u2 >> 16));
    float ra = w0 * a0 + w1 * a1 + w2 * a2;
    float rb = w0 * e0 + w1 * e1 + w2 * e2;
    u32 outp = pack2(ra, rb);
    *(u32*)(merged + (((size_t)b * 8192 + l) * 8 + h) * 64 + d0) = outp;
}

// ---------------------------------------------------------------------------
extern "C" void kernel_launch(void* const* d_in, const int* in_sizes, int n_in,
                              void* d_out, int out_size, void* d_ws, size_t ws_size,
                              hipStream_t stream)
{
    (void)in_sizes; (void)n_in; (void)out_size; (void)ws_size;
    const float* query = (const float*)d_in[0];
    const float* key_  = (const float*)d_in[1];
    const float* value = (const float*)d_in[2];
    const float* Wq    = (const float*)d_in[3];
    const float* Wk    = (const float*)d_in[4];
    const float* Wv    = (const float*)d_in[5];
    const float* Wo    = (const float*)d_in[6];
    const float* bo    = (const float*)d_in[7];

    char* ws = (char*)d_ws;
    const size_t SZ_PROJ = (size_t)16384 * 512 * 2;       // 16 MiB each (bf16)
    const size_t SZ_KG   = (size_t)224 * 1024 * 64 * 2;   // 28 MiB
    const size_t SZ_LG   = (size_t)224 * 1024 * 4;
    u16*   qb     = (u16*)(ws);
    u16*   kb     = (u16*)(ws + SZ_PROJ);
    u16*   vb     = (u16*)(ws + 2 * SZ_PROJ);
    u16*   KG     = (u16*)(ws + 3 * SZ_PROJ);
    u16*   VT     = (u16*)(ws + 3 * SZ_PROJ + SZ_KG);
    u16*   Og     = (u16*)(ws + 3 * SZ_PROJ + 2 * SZ_KG);
    float* Lg     = (float*)(ws + 3 * SZ_PROJ + 3 * SZ_KG);
    u16*   merged = (u16*)(ws + 3 * SZ_PROJ + 3 * SZ_KG + SZ_LG);

    const int M = 16384, N = 512, K = 512;
    // 64^-0.5 * log2(e): scores come out of QK^T in log2 units
    const float SCALE = 0.125f * 1.44269504088896f;

    gemm_bt_bias<true><<<dim3(128, 4), 256, 0, stream>>>(query, Wq, qb, nullptr, nullptr, M, N, K, SCALE);
    gemm_bt_bias<true><<<dim3(128, 4), 256, 0, stream>>>(key_,  Wk, kb, nullptr, nullptr, M, N, K, 1.0f);
    gemm_bt_bias<true><<<dim3(128, 4), 256, 0, stream>>>(value, Wv, vb, nullptr, nullptr, M, N, K, 1.0f);
    gather_kv<<<dim3(224, 32), 256, 0, stream>>>(kb, vb, KG, VT);
    attn_kernel<<<dim3(16, 224), 256, 0, stream>>>(qb, KG, VT, Og, Lg);
    merge_kernel<<<16384, 256, 0, stream>>>(Og, Lg, merged);
    gemm_bt_bias<false><<<dim3(128, 4), 256, 0, stream>>>(merged, Wo, nullptr, (float*)d_out, bo, M, N, K, 1.0f);
}

// Round 9
// 325.013 us; speedup vs baseline: 1.8629x; 1.0507x over previous
//
#include <hip/hip_runtime.h>
#include <hip/hip_bf16.h>

typedef unsigned short u16;
typedef unsigned int u32;
typedef __attribute__((ext_vector_type(8))) short short8;
typedef __attribute__((ext_vector_type(4))) float floatx4;
typedef __attribute__((ext_vector_type(2))) unsigned int uint2v;

__device__ __forceinline__ float b2f(u16 u) {
    u32 x = ((u32)u) << 16;
    return __builtin_bit_cast(float, x);
}
// scalar f32 -> bf16 (RNE), branch-free
__device__ __forceinline__ u16 f2b(float f) {
    u32 x = __builtin_bit_cast(u32, f);
    return (u16)((x + 0x7fffu + ((x >> 16) & 1u)) >> 16);
}
// packed f32x2 -> bf16x2: lowers to single v_cvt_pk_bf16_f32
__device__ __forceinline__ u32 pack2(float lo, float hi) {
    float2 f; f.x = lo; f.y = hi;
    __hip_bfloat162 h = __float22bfloat162_rn(f);
    u32 r;
    __builtin_memcpy(&r, &h, 4);
    return r;
}
// native 2^x (v_exp_f32 computes exp2 directly)
__device__ __forceinline__ float fexp2(float x) {
#if __has_builtin(__builtin_amdgcn_exp2f)
    return __builtin_amdgcn_exp2f(x);
#else
    return __expf(x * 0.6931471805599453f);
#endif
}

// gfx950 permlane32_swap builtin — SAFE ONLY WITH DISTINCT SSA OPERANDS
// (r1/r3 post-mortems: self-swap pl(v,v) aliases result/operand regs = UB).
// HW-verified correct in r4/r5/r7/r8.
// pl32(a,b) -> out[0]=[a.row0,b.row0], out[1]=[a.row1,b.row1] (32-lane rows).
__device__ __forceinline__ uint2v pl32(u32 a, u32 b) {
    return __builtin_amdgcn_permlane32_swap(a, b, false, false);
}

// async global->LDS, 16B per lane. LDS dest = wave-uniform base + lane*16
// (m104/m108); global src is per-lane. Counted by vmcnt; __syncthreads()
// drains it (compiler emits s_waitcnt vmcnt(0) before s_barrier).
__device__ __forceinline__ void gl16(const u16* g, u16* l) {
    __builtin_amdgcn_global_load_lds(
        (const __attribute__((address_space(1))) void*)g,
        (__attribute__((address_space(3))) void*)l, 16, 0, 0);
}

// ---------------------------------------------------------------------------
// Weight pre-convert: f32 -> bf16, PRE-SWIZZLED for gl16 staging:
//   WB[w][n][e ^ ((n&7)*8)] = W[w][n][e]   (XOR hits bits 3-5 of e only)
// grid (4, 128), 256 thr: 4 rows/block, 8 f32 per thread.
// Removes the 128x-redundant per-block B conversion in the GEMMs.
// ---------------------------------------------------------------------------
__global__ __launch_bounds__(256) void conv_w(
    const float* __restrict__ w0, const float* __restrict__ w1,
    const float* __restrict__ w2, const float* __restrict__ w3,
    u16* __restrict__ WB)
{
    int wsel = blockIdx.x;
    const float* src = wsel == 0 ? w0 : wsel == 1 ? w1 : wsel == 2 ? w2 : w3;
    int row = blockIdx.y * 4 + (threadIdx.x >> 6);
    int ch = (threadIdx.x & 63) * 8;
    const float* s = src + (size_t)row * 512 + ch;
    float4 f0 = *(const float4*)s;
    float4 f1 = *(const float4*)(s + 4);
    uint4 pk;
    pk.x = pack2(f0.x, f0.y);
    pk.y = pack2(f0.z, f0.w);
    pk.z = pack2(f1.x, f1.y);
    pk.w = pack2(f1.z, f1.w);
    int dst = ch ^ ((row & 7) * 8);
    *(uint4*)(WB + (size_t)wsel * 262144 + (size_t)row * 512 + dst) = pk;
}

// ---------------------------------------------------------------------------
// GEMM: C[m,n] = scale * sum_k A[m,k] * B[n,k]  (+ bias[n])
// MODE 0: A (M,K) f32, reg-staged+converted into padded LDS.
// MODE 1: A (M,K) bf16 PRE-SWIZZLED ((row&7)*8 XOR), staged via gl16.
// B: (N,K) bf16 PRE-SWIZZLED (conv_w), staged via gl16 in both modes.
// C: bf16 (Cb) or f32 (Cf). 128x128 tile, BK=64.
// ---------------------------------------------------------------------------
template<int MODE>
__global__ __launch_bounds__(256) void gemm_bt_bias(
    const void* __restrict__ Ap, const u16* __restrict__ Bw,
    u16* __restrict__ Cb, float* __restrict__ Cf, const float* __restrict__ bias,
    int N, int K, float scale)
{
    constexpr int APAD = (MODE == 0) ? 72 : 64;
    __shared__ __align__(16) u16 a_lds[128][APAD];
    __shared__ __align__(16) u16 b_lds[128][64];
    const int tid = threadIdx.x;
    const int lane = tid & 63, wv = tid >> 6;
    const int quad = lane >> 4, l15 = lane & 15;
    const int tm = blockIdx.x, tn = blockIdx.y;
    const int wm = (wv >> 1) * 64, wn = (wv & 1) * 64;
    const int bsw = (l15 & 7) * 8;                  // swizzled-read XOR
    u16* alb = &a_lds[0][0];
    u16* blb = &b_lds[0][0];

    floatx4 acc[4][4];
#pragma unroll
    for (int i = 0; i < 4; ++i)
#pragma unroll
        for (int j = 0; j < 4; ++j) acc[i][j] = (floatx4)0.f;

    for (int k0 = 0; k0 < K; k0 += 64) {
        // B staging: 16 KB via 4 gl16/wave from pre-swizzled weights
#pragma unroll
        for (int r = 0; r < 4; ++r) {
            int c = wv * 4 + r;
            gl16(Bw + (size_t)(tn * 128 + c * 8 + (lane >> 3)) * 512
                     + k0 + (lane & 7) * 8,
                 blb + c * 512);
        }
        if constexpr (MODE == 1) {
#pragma unroll
            for (int r = 0; r < 4; ++r) {
                int c = wv * 4 + r;
                gl16((const u16*)Ap + (size_t)(tm * 128 + c * 8 + (lane >> 3)) * 512
                         + k0 + (lane & 7) * 8,
                     alb + c * 512);
            }
        } else {
#pragma unroll
            for (int r = 0; r < 4; ++r) {
                int idx = r * 256 + tid;
                int row = idx >> 3, ch = (idx & 7) * 8;
                const float* A = (const float*)Ap;
                const float* src = A + (size_t)(tm * 128 + row) * K + k0 + ch;
                float4 f0 = *(const float4*)src;
                float4 f1 = *(const float4*)(src + 4);
                uint4 pk;
                pk.x = pack2(f0.x, f0.y);
                pk.y = pack2(f0.z, f0.w);
                pk.z = pack2(f1.x, f1.y);
                pk.w = pack2(f1.z, f1.w);
                *(uint4*)&a_lds[row][ch] = pk;
            }
        }
        __syncthreads();
#pragma unroll
        for (int dc = 0; dc < 2; ++dc) {
            short8 af[4], bf[4];
#pragma unroll
            for (int mi = 0; mi < 4; ++mi) {
                int col = dc * 32 + quad * 8;
                if constexpr (MODE == 1) col ^= bsw;
                af[mi] = *(const short8*)&a_lds[wm + mi * 16 + l15][col];
            }
#pragma unroll
            for (int ni = 0; ni < 4; ++ni)
                bf[ni] = *(const short8*)&b_lds[wn + ni * 16 + l15][(dc * 32 + quad * 8) ^ bsw];
#pragma unroll
            for (int mi = 0; mi < 4; ++mi)
#pragma unroll
                for (int ni = 0; ni < 4; ++ni)
                    acc[mi][ni] = __builtin_amdgcn_mfma_f32_16x16x32_bf16(
                        af[mi], bf[ni], acc[mi][ni], 0, 0, 0);
        }
        __syncthreads();
    }
#pragma unroll
    for (int mi = 0; mi < 4; ++mi)
#pragma unroll
        for (int ni = 0; ni < 4; ++ni) {
            int col = tn * 128 + wn + ni * 16 + l15;
            float bb = bias ? bias[col] : 0.f;
#pragma unroll
            for (int r = 0; r < 4; ++r) {
                int row = tm * 128 + wm + mi * 16 + quad * 4 + r;
                float val = acc[mi][ni][r] * scale + bb;
                if (Cf) Cf[(size_t)row * N + col] = val;
                else    Cb[(size_t)row * N + col] = f2b(val);
            }
        }
}

// ---------------------------------------------------------------------------
// instance decode: 224 instances = 128 (br0) + 64 (br1) + 32 (br2)
// ---------------------------------------------------------------------------
__device__ __forceinline__ void decode_inst(int inst, int& b, int& s, int& h,
                                            int& sl, int& dr, int& phase)
{
    if (inst < 128)      { int j = inst;       b = j >> 6; s = (j >> 3) & 7; h = j & 7; sl = 1024; dr = 1; phase = 0;      }
    else if (inst < 192) { int j = inst - 128; b = j >> 5; s = (j >> 3) & 3; h = j & 7; sl = 2048; dr = 2; phase = h >> 2; }
    else                 { int j = inst - 192; b = j >> 4; s = (j >> 3) & 1; h = j & 7; sl = 4096; dr = 4; phase = h >> 1; }
}

// ---------------------------------------------------------------------------
// Gather K and V^T into per-instance contiguous buffers (internal bf16),
// PRE-SWIZZLED for the attn kernel's global_load_lds staging (rule 21:
// both-sides-or-neither). Within each 128-key staging tile:
//   KG'[n][e]  = K[n][e ^ ((n&7)*8)]
//   VT'[d][c]  = V^T[d][c ^ ((d&7)*8)]
// KG[inst][n][d'], VT[inst][d][c']. grid: (224, 32)
// ---------------------------------------------------------------------------
__global__ __launch_bounds__(256) void gather_kv(
    const u16* __restrict__ kk, const u16* __restrict__ vv,
    u16* __restrict__ KG, u16* __restrict__ VT)
{
    int inst = blockIdx.x;
    int b, s, h, sl, dr, phase;
    decode_inst(inst, b, s, h, sl, dr, phase);
    int n0 = blockIdx.y * 32;
    __shared__ __align__(16) u16 tile[32][72];
    int tid = threadIdx.x;
    int row = tid >> 3, ch = (tid & 7) * 8;
    int n = n0 + row;
    size_t pos = (size_t)s * sl + (size_t)n * dr + phase;
    size_t src = (((size_t)b * 8192 + pos) * 8 + h) * 64 + ch;
    int chs = ch ^ ((n & 7) * 8);   // K column swizzle (8-aligned, stays 0..63)
    *(uint4*)(KG + ((size_t)inst * 1024 + n) * 64 + chs) = *(const uint4*)(kk + src);
    *(uint4*)&tile[row][ch] = *(const uint4*)(vv + src);
    __syncthreads();
    int d = tid >> 2, nn = (tid & 3) * 8;
    __align__(16) u16 tmp[8];
#pragma unroll
    for (int j = 0; j < 8; ++j) tmp[j] = tile[nn + j][d];
    int col = (n0 + nn) ^ ((d & 7) * 8);  // VT column swizzle (within 128-block)
    *(uint4*)(VT + ((size_t)inst * 64 + d) * 1024 + col) = *(uint4*)tmp;
}

// ---------------------------------------------------------------------------
// Flash attention, S^T formulation; scores arrive in LOG2 domain (log2e folded
// into Q-proj scale); softmax via native v_exp_f32. LSE kept in log2 units.
// grid: (16 q-tiles, 224 inst); 256 thr = 4 waves x 16 q-rows; K-tile 128.
// r7: global_load_lds staging with pre-swizzled KG/VT. r8: MFMA row-sum
// (all-ones A) + T13 defer-max + tree max. sl15 + dual-permlane32 PV
// transpose (HW-verified r4+).
// ---------------------------------------------------------------------------
__global__ __launch_bounds__(256, 4) void attn_kernel(
    const u16* __restrict__ q, const u16* __restrict__ KG,
    const u16* __restrict__ VT, u16* __restrict__ Og, float* __restrict__ Lg)
{
    const int inst = blockIdx.y, qt = blockIdx.x;
    int b, s, h, sl, dr, phase;
    decode_inst(inst, b, s, h, sl, dr, phase);
    __shared__ __align__(16) u16 k_lds[128][64];   // 16 KB, swizzled cols
    __shared__ __align__(16) u16 vt_lds[64][128];  // 16 KB, swizzled cols
    const int tid = threadIdx.x, lane = tid & 63, wv = tid >> 6;
    const int quad = lane >> 4, l15 = lane & 15;
    const int sl15 = (l15 & 3) | ((l15 & 4) << 1) | ((l15 & 8) >> 1);
    const int ksw = (sl15 & 7) * 8;
    const int vsw = (l15 & 7) * 8;

    const int qrow = qt * 64 + wv * 16 + l15;
    const size_t qpos = (size_t)s * sl + (size_t)qrow * dr + phase;
    const u16* qbase = q + (((size_t)b * 8192 + qpos) * 8 + h) * 64;
    const short8 qf0 = *(const short8*)(qbase + quad * 8);
    const short8 qf1 = *(const short8*)(qbase + 32 + quad * 8);

    uint4 onesw;
    onesw.x = 0x3F803F80u; onesw.y = 0x3F803F80u;
    onesw.z = 0x3F803F80u; onesw.w = 0x3F803F80u;
    const short8 vones = __builtin_bit_cast(short8, onesw);

    floatx4 oacc[4];
#pragma unroll
    for (int dt = 0; dt < 4; ++dt) oacc[dt] = (floatx4)0.f;
    floatx4 racc = (floatx4)0.f;
    float mst = -1e30f;

    const u16* KGb = KG + (size_t)inst * 65536;
    const u16* VTb = VT + (size_t)inst * 65536;
    u16* klb = &k_lds[0][0];
    u16* vlb = &vt_lds[0][0];

    for (int it = 0; it < 8; ++it) {
        const int k0 = it * 128;
#pragma unroll
        for (int r = 0; r < 4; ++r) {
            int c = wv * 4 + r;
            gl16(KGb + (size_t)k0 * 64 + c * 512 + lane * 8, klb + c * 512);
            gl16(VTb + (size_t)(c * 4 + (lane >> 4)) * 1024 + k0 + (lane & 15) * 8,
                 vlb + c * 512);
        }
        __syncthreads();

        floatx4 sacc[8];
#pragma unroll
        for (int nt = 0; nt < 8; ++nt) {
            sacc[nt] = (floatx4)0.f;
            short8 kf0 = *(const short8*)&k_lds[nt * 16 + sl15][(quad * 8) ^ ksw];
            short8 kf1 = *(const short8*)&k_lds[nt * 16 + sl15][(32 + quad * 8) ^ ksw];
            sacc[nt] = __builtin_amdgcn_mfma_f32_16x16x32_bf16(kf0, qf0, sacc[nt], 0, 0, 0);
            sacc[nt] = __builtin_amdgcn_mfma_f32_16x16x32_bf16(kf1, qf1, sacc[nt], 0, 0, 0);
        }

        float t0, t1;
        {
            float m0 = fmaxf(fmaxf(sacc[0][0], sacc[0][1]), fmaxf(sacc[0][2], sacc[0][3]));
            float m1 = fmaxf(fmaxf(sacc[1][0], sacc[1][1]), fmaxf(sacc[1][2], sacc[1][3]));
            float m2 = fmaxf(fmaxf(sacc[2][0], sacc[2][1]), fmaxf(sacc[2][2], sacc[2][3]));
            float m3 = fmaxf(fmaxf(sacc[3][0], sacc[3][1]), fmaxf(sacc[3][2], sacc[3][3]));
            t0 = fmaxf(fmaxf(m0, m1), fmaxf(m2, m3));
            float m4 = fmaxf(fmaxf(sacc[4][0], sacc[4][1]), fmaxf(sacc[4][2], sacc[4][3]));
            float m5 = fmaxf(fmaxf(sacc[5][0], sacc[5][1]), fmaxf(sacc[5][2], sacc[5][3]));
            float m6 = fmaxf(fmaxf(sacc[6][0], sacc[6][1]), fmaxf(sacc[6][2], sacc[6][3]));
            float m7 = fmaxf(fmaxf(sacc[7][0], sacc[7][1]), fmaxf(sacc[7][2], sacc[7][3]));
            t1 = fmaxf(fmaxf(m4, m5), fmaxf(m6, m7));
        }
        float mx = fmaxf(t0, t1);
        mx = fmaxf(mx, __shfl_xor(mx, 16, 64));
        mx = fmaxf(mx, __shfl_xor(mx, 32, 64));

        if (!__all(mx - mst <= 8.f)) {
            float mnew = fmaxf(mst, mx);
            float alpha = fexp2(mst - mnew);
#pragma unroll
            for (int dt = 0; dt < 4; ++dt) oacc[dt] *= alpha;
            racc *= alpha;
            mst = mnew;
        }

#pragma unroll
        for (int nt = 0; nt < 8; ++nt)
#pragma unroll
            for (int r = 0; r < 4; ++r)
                sacc[nt][r] = fexp2(sacc[nt][r] - mst);

#pragma unroll
        for (int nc = 0; nc < 4; ++nc) {
            u32 pk00 = pack2(sacc[2 * nc][0], sacc[2 * nc][1]);
            u32 pk01 = pack2(sacc[2 * nc][2], sacc[2 * nc][3]);
            u32 pk10 = pack2(sacc[2 * nc + 1][0], sacc[2 * nc + 1][1]);
            u32 pk11 = pack2(sacc[2 * nc + 1][2], sacc[2 * nc + 1][3]);
            uint2v xz = pl32(pk00, pk10);
            uint2v yw = pl32(pk01, pk11);
            uint4 bw;
            bw.x = xz[0];
            bw.y = yw[0];
            bw.z = xz[1];
            bw.w = yw[1];
            short8 pf = __builtin_bit_cast(short8, bw);
#pragma unroll
            for (int dt = 0; dt < 4; ++dt) {
                short8 vf = *(const short8*)
                    &vt_lds[dt * 16 + l15][(nc * 32 + quad * 8) ^ vsw];
                oacc[dt] = __builtin_amdgcn_mfma_f32_16x16x32_bf16(vf, pf, oacc[dt], 0, 0, 0);
            }
            racc = __builtin_amdgcn_mfma_f32_16x16x32_bf16(vones, pf, racc, 0, 0, 0);
        }
        __syncthreads();
    }

    const int esw = (l15 & 7) * 8;
    float lst = racc[0];
    float inv_l = (lst > 0.f) ? (1.f / lst) : 0.f;
#pragma unroll
    for (int dt = 0; dt < 4; ++dt) {
        u32 lo = pack2(oacc[dt][0] * inv_l, oacc[dt][1] * inv_l);
        u32 hi = pack2(oacc[dt][2] * inv_l, oacc[dt][3] * inv_l);
        uint2 v; v.x = lo; v.y = hi;
        *(uint2*)&k_lds[wv * 16 + l15][(dt * 16 + quad * 4) ^ esw] = v;
    }
    __syncthreads();
#pragma unroll
    for (int c = 0; c < 2; ++c) {
        uint4 val = *(const uint4*)&k_lds[wv * 16 + l15][(quad * 16 + c * 8) ^ esw];
        *(uint4*)(Og + (((size_t)inst * 1024 + qt * 64 + wv * 16 + l15) * 64
                        + quad * 16 + c * 8)) = val;
    }
    if (quad == 0) {
        Lg[(size_t)inst * 1024 + qt * 64 + wv * 16 + l15] = mst + __log2f(lst);
    }
}

// ---------------------------------------------------------------------------
// LSE-weighted merge (log2-domain LSE) -> merged (b, L, H*64) bf16,
// written PRE-SWIZZLED (col d0 ^ ((l&7)*8) within each head's 64-block) so
// the final GEMM can gl16-stage it (rule 21: both-sides-or-neither).
// ---------------------------------------------------------------------------
__global__ __launch_bounds__(256) void merge_kernel(
    const u16* __restrict__ Og, const float* __restrict__ Lg,
    u16* __restrict__ merged)
{
    int bid = blockIdx.x;
    int b = bid >> 13, l = bid & 8191;
    int t = threadIdx.x;
    int h = t >> 5, d0 = (t & 31) * 2;

    int inst0 = b * 64 + ((l >> 10) << 3) + h;
    int row0 = l & 1023;
    int p1 = l & 2047;
    bool c1 = ((p1 & 1) == (h >> 2));
    int inst1 = 128 + b * 32 + ((l >> 11) << 3) + h;
    int row1 = p1 >> 1;
    int p2 = l & 4095;
    bool c2 = ((p2 & 3) == (h >> 1));
    int inst2 = 192 + b * 16 + ((l >> 12) << 3) + h;
    int row2 = p2 >> 2;

    float lse0 = Lg[(size_t)inst0 * 1024 + row0];
    float lse1 = c1 ? Lg[(size_t)inst1 * 1024 + row1] : -1e30f;
    float lse2 = c2 ? Lg[(size_t)inst2 * 1024 + row2] : -1e30f;
    float m = fmaxf(lse0, fmaxf(lse1, lse2));
    float w0 = fexp2(lse0 - m);
    float w1 = c1 ? fexp2(lse1 - m) : 0.f;
    float w2 = c2 ? fexp2(lse2 - m) : 0.f;
    float inv = 1.f / (w0 + w1 + w2);
    w0 *= inv; w1 *= inv; w2 *= inv;

    u32 u0 = *(const u32*)(Og + ((size_t)inst0 * 1024 + row0) * 64 + d0);
    u32 u1 = c1 ? *(const u32*)(Og + ((size_t)inst1 * 1024 + row1) * 64 + d0) : 0u;
    u32 u2 = c2 ? *(const u32*)(Og + ((size_t)inst2 * 1024 + row2) * 64 + d0) : 0u;
    float a0 = b2f((u16)(u0 & 0xffff)), e0 = b2f((u16)(u0 >> 16));
    float a1 = b2f((u16)(u1 & 0xffff)), e1 = b2f((u16)(u1 >> 16));
    float a2 = b2f((u16)(u2 & 0xffff)), e2 = b2f((u16)(u2 >> 16));
    float ra = w0 * a0 + w1 * a1 + w2 * a2;
    float rb = w0 * e0 + w1 * e1 + w2 * e2;
    u32 outp = pack2(ra, rb);
    int d0s = d0 ^ ((l & 7) * 8);   // pre-swizzle for final GEMM gl16 staging
    *(u32*)(merged + (((size_t)b * 8192 + l) * 8 + h) * 64 + d0s) = outp;
}

// ---------------------------------------------------------------------------
extern "C" void kernel_launch(void* const* d_in, const int* in_sizes, int n_in,
                              void* d_out, int out_size, void* d_ws, size_t ws_size,
                              hipStream_t stream)
{
    (void)in_sizes; (void)n_in; (void)out_size; (void)ws_size;
    const float* query = (const float*)d_in[0];
    const float* key_  = (const float*)d_in[1];
    const float* value = (const float*)d_in[2];
    const float* Wq    = (const float*)d_in[3];
    const float* Wk    = (const float*)d_in[4];
    const float* Wv    = (const float*)d_in[5];
    const float* Wo    = (const float*)d_in[6];
    const float* bo    = (const float*)d_in[7];

    char* ws = (char*)d_ws;
    const size_t SZ_PROJ = (size_t)16384 * 512 * 2;       // 16 MiB each (bf16)
    const size_t SZ_KG   = (size_t)224 * 1024 * 64 * 2;   // 28 MiB
    const size_t SZ_LG   = (size_t)224 * 1024 * 4;
    u16*   qb     = (u16*)(ws);
    u16*   kb     = (u16*)(ws + SZ_PROJ);
    u16*   vb     = (u16*)(ws + 2 * SZ_PROJ);
    u16*   KG     = (u16*)(ws + 3 * SZ_PROJ);
    u16*   VT     = (u16*)(ws + 3 * SZ_PROJ + SZ_KG);
    u16*   Og     = (u16*)(ws + 3 * SZ_PROJ + 2 * SZ_KG);
    float* Lg     = (float*)(ws + 3 * SZ_PROJ + 3 * SZ_KG);
    u16*   merged = (u16*)(ws + 3 * SZ_PROJ + 3 * SZ_KG + SZ_LG);
    u16*   WB     = (u16*)(ws + 3 * SZ_PROJ + 3 * SZ_KG + SZ_LG + SZ_PROJ);

    const int N = 512, K = 512;
    // 64^-0.5 * log2(e): scores come out of QK^T in log2 units
    const float SCALE = 0.125f * 1.44269504088896f;

    conv_w<<<dim3(4, 128), 256, 0, stream>>>(Wq, Wk, Wv, Wo, WB);
    gemm_bt_bias<0><<<dim3(128, 4), 256, 0, stream>>>(query, WB,              qb, nullptr, nullptr, N, K, SCALE);
    gemm_bt_bias<0><<<dim3(128, 4), 256, 0, stream>>>(key_,  WB + 262144,     kb, nullptr, nullptr, N, K, 1.0f);
    gemm_bt_bias<0><<<dim3(128, 4), 256, 0, stream>>>(value, WB + 2 * 262144, vb, nullptr, nullptr, N, K, 1.0f);
    gather_kv<<<dim3(224, 32), 256, 0, stream>>>(kb, vb, KG, VT);
    attn_kernel<<<dim3(16, 224), 256, 0, stream>>>(qb, KG, VT, Og, Lg);
    merge_kernel<<<16384, 256, 0, stream>>>(Og, Lg, merged);
    gemm_bt_bias<1><<<dim3(128, 4), 256, 0, stream>>>(merged, WB + 3 * 262144, nullptr, (float*)d_out, bo, N, K, 1.0f);
}